// Round 1
// 2707.473 us; speedup vs baseline: 1.1679x; 1.1679x over previous
//
#include <hip/hip_runtime.h>
#include <hip/hip_bf16.h>
#include <math.h>

// Problem constants (from reference)
constexpr int S   = 512;
constexpr int D   = 2048;
constexpr int H   = 16;
constexpr int HD  = 128;
constexpr int T   = 512;     // B*S
constexpr int E   = 64;
constexpr int I_  = 512;
constexpr int G   = 8;
constexpr int TKG = 4;
constexpr int TK  = 6;
constexpr int SH_I = 1024;
constexpr float ROUTE_SCALE = 2.5f;
constexpr float EPS = 1e-5f;

// ---------------------------------------------------------------- rmsnorm
__global__ __launch_bounds__(256) void rmsnorm_kernel(const float* __restrict__ x,
                                                      const float* __restrict__ w,
                                                      float* __restrict__ out) {
    int t = blockIdx.x;
    int tid = threadIdx.x;
    const float* row = x + (size_t)t * D;
    float ss = 0.f;
    for (int i = tid; i < D; i += 256) { float v = row[i]; ss += v * v; }
    for (int o = 32; o; o >>= 1) ss += __shfl_down(ss, o, 64);
    __shared__ float red[4];
    if ((tid & 63) == 0) red[tid >> 6] = ss;
    __syncthreads();
    float tot = red[0] + red[1] + red[2] + red[3];
    float scale = rsqrtf(tot / (float)D + EPS);
    for (int i = tid; i < D; i += 256) out[(size_t)t * D + i] = row[i] * scale * w[i];
}

// ---------------------------------------------------------------- high-ILP GEMM: C = A(MxK) @ B(NxK)^T (+ addsrc)
// 128 threads, BM=64, BN=64, BK=32, per-thread 8x4, double-buffered LDS.
// blockIdx.z selects (B,C) pair so QKV / sw1-sw3 fuse into one launch.
// Requires M%64==0, N%64==0, K%32==0.
__global__ __launch_bounds__(128) void gemm_nt_kernel(const float* __restrict__ A,
                                                      const float* __restrict__ B0,
                                                      const float* __restrict__ B1,
                                                      const float* __restrict__ B2,
                                                      float* __restrict__ C0,
                                                      float* __restrict__ C1,
                                                      float* __restrict__ C2,
                                                      const float* __restrict__ addsrc,
                                                      int M, int N, int K) {
    const float* B = (blockIdx.z == 0) ? B0 : ((blockIdx.z == 1) ? B1 : B2);
    float*       C = (blockIdx.z == 0) ? C0 : ((blockIdx.z == 1) ? C1 : C2);
    __shared__ float As[2][32][64];   // k-major: As[k][m], b128 reads conflict-free
    __shared__ float Bs[2][32][64];
    const int m0 = blockIdx.y * 64, n0 = blockIdx.x * 64;
    const int tid = threadIdx.x;
    const int ty = tid >> 4;          // 0..7  -> 8 rows each
    const int tx = tid & 15;          // 0..15 -> 4 cols each
    const int sr  = tid & 63;         // staging row (2-way LDS write, free)
    const int sc0 = tid >> 6;         // 0 or 1; c4 = sc0 + 2*it
    const float* Arow = A + (size_t)(m0 + sr) * K;
    const float* Brow = B + (size_t)(n0 + sr) * K;

    float c[8][4] = {};
    float4 ra[4], rb[4];

    // prologue: stage k-tile 0 into buffer 0
#pragma unroll
    for (int it = 0; it < 4; ++it) {
        int c4 = sc0 + 2 * it;
        ra[it] = *(const float4*)(Arow + c4 * 4);
        rb[it] = *(const float4*)(Brow + c4 * 4);
    }
#pragma unroll
    for (int it = 0; it < 4; ++it) {
        int c4 = sc0 + 2 * it;
        As[0][c4 * 4 + 0][sr] = ra[it].x; As[0][c4 * 4 + 1][sr] = ra[it].y;
        As[0][c4 * 4 + 2][sr] = ra[it].z; As[0][c4 * 4 + 3][sr] = ra[it].w;
        Bs[0][c4 * 4 + 0][sr] = rb[it].x; Bs[0][c4 * 4 + 1][sr] = rb[it].y;
        Bs[0][c4 * 4 + 2][sr] = rb[it].z; Bs[0][c4 * 4 + 3][sr] = rb[it].w;
    }
    __syncthreads();

    const int KT = K >> 5;
    for (int kt = 0; kt < KT; ++kt) {
        const int cur = kt & 1;
        if (kt + 1 < KT) {
            const float* Ar = Arow + (kt + 1) * 32;
            const float* Br = Brow + (kt + 1) * 32;
#pragma unroll
            for (int it = 0; it < 4; ++it) {
                int c4 = sc0 + 2 * it;
                ra[it] = *(const float4*)(Ar + c4 * 4);
                rb[it] = *(const float4*)(Br + c4 * 4);
            }
        }
#pragma unroll
        for (int kk = 0; kk < 32; ++kk) {
            float4 a0 = *(const float4*)&As[cur][kk][ty * 8];
            float4 a1 = *(const float4*)&As[cur][kk][ty * 8 + 4];
            float4 b0 = *(const float4*)&Bs[cur][kk][tx * 4];
            float a[8] = {a0.x, a0.y, a0.z, a0.w, a1.x, a1.y, a1.z, a1.w};
            float b[4] = {b0.x, b0.y, b0.z, b0.w};
#pragma unroll
            for (int i = 0; i < 8; ++i)
#pragma unroll
                for (int j = 0; j < 4; ++j) c[i][j] = fmaf(a[i], b[j], c[i][j]);
        }
        if (kt + 1 < KT) {
            const int nxt = cur ^ 1;
#pragma unroll
            for (int it = 0; it < 4; ++it) {
                int c4 = sc0 + 2 * it;
                As[nxt][c4 * 4 + 0][sr] = ra[it].x; As[nxt][c4 * 4 + 1][sr] = ra[it].y;
                As[nxt][c4 * 4 + 2][sr] = ra[it].z; As[nxt][c4 * 4 + 3][sr] = ra[it].w;
                Bs[nxt][c4 * 4 + 0][sr] = rb[it].x; Bs[nxt][c4 * 4 + 1][sr] = rb[it].y;
                Bs[nxt][c4 * 4 + 2][sr] = rb[it].z; Bs[nxt][c4 * 4 + 3][sr] = rb[it].w;
            }
        }
        __syncthreads();
    }

#pragma unroll
    for (int i = 0; i < 8; ++i) {
        size_t off = (size_t)(m0 + ty * 8 + i) * N + n0 + tx * 4;
        float4 o;
        o.x = c[i][0]; o.y = c[i][1]; o.z = c[i][2]; o.w = c[i][3];
        if (addsrc) {
            float4 ad = *(const float4*)(addsrc + off);
            o.x += ad.x; o.y += ad.y; o.z += ad.z; o.w += ad.w;
        }
        *(float4*)(C + off) = o;
    }
}

// ---------------------------------------------------------------- RoPE (in-place on q and k)
__global__ __launch_bounds__(256) void rope_kernel(float* __restrict__ q, float* __restrict__ k,
                                                   const float* __restrict__ fc,
                                                   const float* __restrict__ fs) {
    int idx = blockIdx.x * 256 + threadIdx.x;   // T*H*(HD/2)
    int p  = idx & (HD / 2 - 1);
    int hh = (idx >> 6) & (H - 1);
    int t  = idx >> 10;
    float c = fc[t * (HD / 2) + p], s = fs[t * (HD / 2) + p];
    size_t base = (size_t)t * D + hh * HD + p * 2;
    float re = q[base], im = q[base + 1];
    q[base]     = re * c - im * s;
    q[base + 1] = re * s + im * c;
    re = k[base]; im = k[base + 1];
    k[base]     = re * c - im * s;
    k[base + 1] = re * s + im * c;
}

// ---------------------------------------------------------------- attention: one block per (q-row, head)
__global__ __launch_bounds__(256) void attn_kernel(const float* __restrict__ q,
                                                   const float* __restrict__ k,
                                                   const float* __restrict__ v,
                                                   float* __restrict__ o) {
    int qi = blockIdx.x, hh = blockIdx.y, tid = threadIdx.x;
    __shared__ float qs[HD];
    __shared__ float sc[S];
    __shared__ float redm[4];
    __shared__ float redz[4];
    __shared__ float part[256];
    if (tid < HD) qs[tid] = q[(size_t)qi * D + hh * HD + tid];
    __syncthreads();
    int kn = qi + 1;            // causal
    float lmax = -1e30f;
    for (int kk = tid; kk < kn; kk += 256) {
        const float4* k4 = (const float4*)(k + (size_t)kk * D + hh * HD);
        const float4* q4 = (const float4*)qs;
        float s = 0.f;
#pragma unroll
        for (int d4 = 0; d4 < HD / 4; d4++) {
            float4 kvv = k4[d4], qvv = q4[d4];
            s += qvv.x * kvv.x + qvv.y * kvv.y + qvv.z * kvv.z + qvv.w * kvv.w;
        }
        s *= 0.08838834764831845f;   // 1/sqrt(128)
        sc[kk] = s;
        lmax = fmaxf(lmax, s);
    }
    for (int o2 = 32; o2; o2 >>= 1) lmax = fmaxf(lmax, __shfl_down(lmax, o2, 64));
    if ((tid & 63) == 0) redm[tid >> 6] = lmax;
    __syncthreads();
    float M_ = fmaxf(fmaxf(redm[0], redm[1]), fmaxf(redm[2], redm[3]));
    float lsum = 0.f;
    for (int kk = tid; kk < kn; kk += 256) {
        float e2 = expf(sc[kk] - M_);
        sc[kk] = e2;
        lsum += e2;
    }
    for (int o2 = 32; o2; o2 >>= 1) lsum += __shfl_down(lsum, o2, 64);
    if ((tid & 63) == 0) redz[tid >> 6] = lsum;
    __syncthreads();
    float Z = redz[0] + redz[1] + redz[2] + redz[3];
    int d2 = tid & (HD - 1);
    int halfsel = tid >> 7;
    float acc = 0.f;
    for (int kk = halfsel; kk < kn; kk += 2)
        acc += sc[kk] * v[(size_t)kk * D + hh * HD + d2];
    part[tid] = acc;
    __syncthreads();
    if (tid < HD) o[(size_t)qi * D + hh * HD + tid] = (part[tid] + part[tid + HD]) / Z;
}

// ---------------------------------------------------------------- gate logits: one block per token (skinny N=64)
__global__ __launch_bounds__(256) void gate_kernel(const float* __restrict__ tbuf,
                                                   const float* __restrict__ gate_w,
                                                   float* __restrict__ logits) {
    int tok = blockIdx.x;
    int e    = threadIdx.x >> 2;   // 0..63
    int part = threadIdx.x & 3;    // 0..3
    const float* trow = tbuf   + (size_t)tok * D;
    const float* wrow = gate_w + (size_t)e * D;
    float s = 0.f;
    for (int k = part * 4; k < D; k += 16) {
        float4 a = *(const float4*)(trow + k);
        float4 b = *(const float4*)(wrow + k);
        s += a.x * b.x + a.y * b.y + a.z * b.z + a.w * b.w;
    }
    s += __shfl_down(s, 1, 4);
    s += __shfl_down(s, 2, 4);
    if (part == 0) logits[(size_t)tok * E + e] = s;
}

// ---------------------------------------------------------------- routing (sigmoid gate + group top-k + expert top-k)
__global__ __launch_bounds__(64) void routing_kernel(const float* __restrict__ logits,
                                                     float* __restrict__ gw,
                                                     int* __restrict__ counts,
                                                     int* __restrict__ elist) {
    int t = blockIdx.x;
    int lane = threadIdx.x;
    __shared__ float ss[E];
    if (lane < E) ss[lane] = 1.f / (1.f + expf(-logits[(size_t)t * E + lane]));
    __syncthreads();
    if (lane == 0) {
        float gs[G];
        for (int g = 0; g < G; g++) {
            float m = ss[g * 8];
            for (int j = 1; j < 8; j++) m = fmaxf(m, ss[g * 8 + j]);
            gs[g] = m;
        }
        bool keep[G];
        for (int g = 0; g < G; g++) keep[g] = false;
        for (int r = 0; r < TKG; r++) {
            int best = -1; float bv = -1e30f;
            for (int g = 0; g < G; g++)
                if (!keep[g] && gs[g] > bv) { bv = gs[g]; best = g; }
            keep[best] = true;
        }
        float masked[E];
        for (int e2 = 0; e2 < E; e2++) masked[e2] = keep[e2 >> 3] ? ss[e2] : -1e30f;
        int chosen[TK]; float w[TK]; float wsum = 0.f;
        for (int r = 0; r < TK; r++) {
            int best = 0; float bv = -1e31f;
            for (int e2 = 0; e2 < E; e2++)
                if (masked[e2] > bv) { bv = masked[e2]; best = e2; }
            chosen[r] = best; w[r] = ss[best]; masked[best] = -1e31f; wsum += w[r];
        }
        float scale_ = ROUTE_SCALE / wsum;
        for (int r = 0; r < TK; r++) {
            int slot = t * TK + r;
            gw[slot] = w[r] * scale_;
            int e2 = chosen[r];
            int pos = atomicAdd(&counts[e2], 1);
            elist[e2 * T + pos] = slot;
        }
    }
}

// ---------------------------------------------------------------- MoE up: a[slot, i] = silu(t@w1^T) * (t@w3^T)
// 128 threads, BM=64 slots, BN=64 of I, BK=16, per-thread 8x4 for each of c1/c3, double-buffered.
__global__ __launch_bounds__(128) void moe_up_kernel(const float* __restrict__ tbuf,
                                                     const float* __restrict__ w1,
                                                     const float* __restrict__ w3,
                                                     const int* __restrict__ counts,
                                                     const int* __restrict__ elist,
                                                     float* __restrict__ abuf) {
    const int e = blockIdx.x;
    const int nt = counts[e];
    if (nt == 0) return;
    const int i0 = blockIdx.y * 64;
    const float* W1 = w1 + (size_t)e * I_ * D;
    const float* W3 = w3 + (size_t)e * I_ * D;
    __shared__ float As[2][16][64], B1s[2][16][64], B3s[2][16][64];
    __shared__ int slots[64];
    __shared__ const float* rows[64];
    const int tid = threadIdx.x;
    const int ty = tid >> 4, tx = tid & 15;
    const int sr  = tid & 63;
    const int sc0 = tid >> 6;     // c4 = sc0 + 2*it, it 0..1 -> c4 0..3 (16 k's)
    const float* B1row = W1 + (size_t)(i0 + sr) * D;
    const float* B3row = W3 + (size_t)(i0 + sr) * D;

    for (int tb = 0; tb < nt; tb += 64) {
        if (tid < 64) {
            int sl = (tb + tid < nt) ? elist[e * T + tb + tid] : -1;
            slots[tid] = sl;
            rows[tid] = (sl >= 0) ? (tbuf + (size_t)(sl / TK) * D) : nullptr;
        }
        __syncthreads();
        const float* Arow = rows[sr];
        float c1[8][4] = {}, c3[8][4] = {};
        float4 ra[2], rb1[2], rb3[2];
        // prologue: k-tile 0
#pragma unroll
        for (int it = 0; it < 2; ++it) {
            int c4 = sc0 + 2 * it;
            ra[it]  = Arow ? *(const float4*)(Arow + c4 * 4) : make_float4(0.f, 0.f, 0.f, 0.f);
            rb1[it] = *(const float4*)(B1row + c4 * 4);
            rb3[it] = *(const float4*)(B3row + c4 * 4);
        }
#pragma unroll
        for (int it = 0; it < 2; ++it) {
            int c4 = sc0 + 2 * it;
            As[0][c4 * 4 + 0][sr] = ra[it].x;  As[0][c4 * 4 + 1][sr] = ra[it].y;
            As[0][c4 * 4 + 2][sr] = ra[it].z;  As[0][c4 * 4 + 3][sr] = ra[it].w;
            B1s[0][c4 * 4 + 0][sr] = rb1[it].x; B1s[0][c4 * 4 + 1][sr] = rb1[it].y;
            B1s[0][c4 * 4 + 2][sr] = rb1[it].z; B1s[0][c4 * 4 + 3][sr] = rb1[it].w;
            B3s[0][c4 * 4 + 0][sr] = rb3[it].x; B3s[0][c4 * 4 + 1][sr] = rb3[it].y;
            B3s[0][c4 * 4 + 2][sr] = rb3[it].z; B3s[0][c4 * 4 + 3][sr] = rb3[it].w;
        }
        __syncthreads();

        const int KT = D / 16;   // 128
        for (int kt = 0; kt < KT; ++kt) {
            const int cur = kt & 1;
            if (kt + 1 < KT) {
                const int k0 = (kt + 1) * 16;
#pragma unroll
                for (int it = 0; it < 2; ++it) {
                    int c4 = sc0 + 2 * it;
                    ra[it]  = Arow ? *(const float4*)(Arow + k0 + c4 * 4) : make_float4(0.f, 0.f, 0.f, 0.f);
                    rb1[it] = *(const float4*)(B1row + k0 + c4 * 4);
                    rb3[it] = *(const float4*)(B3row + k0 + c4 * 4);
                }
            }
#pragma unroll
            for (int kk = 0; kk < 16; ++kk) {
                float4 a0 = *(const float4*)&As[cur][kk][ty * 8];
                float4 a1 = *(const float4*)&As[cur][kk][ty * 8 + 4];
                float4 v1 = *(const float4*)&B1s[cur][kk][tx * 4];
                float4 v3 = *(const float4*)&B3s[cur][kk][tx * 4];
                float a[8]  = {a0.x, a0.y, a0.z, a0.w, a1.x, a1.y, a1.z, a1.w};
                float b1v[4] = {v1.x, v1.y, v1.z, v1.w};
                float b3v[4] = {v3.x, v3.y, v3.z, v3.w};
#pragma unroll
                for (int i = 0; i < 8; ++i) {
#pragma unroll
                    for (int j = 0; j < 4; ++j) {
                        c1[i][j] = fmaf(a[i], b1v[j], c1[i][j]);
                        c3[i][j] = fmaf(a[i], b3v[j], c3[i][j]);
                    }
                }
            }
            if (kt + 1 < KT) {
                const int nxt = cur ^ 1;
#pragma unroll
                for (int it = 0; it < 2; ++it) {
                    int c4 = sc0 + 2 * it;
                    As[nxt][c4 * 4 + 0][sr] = ra[it].x;  As[nxt][c4 * 4 + 1][sr] = ra[it].y;
                    As[nxt][c4 * 4 + 2][sr] = ra[it].z;  As[nxt][c4 * 4 + 3][sr] = ra[it].w;
                    B1s[nxt][c4 * 4 + 0][sr] = rb1[it].x; B1s[nxt][c4 * 4 + 1][sr] = rb1[it].y;
                    B1s[nxt][c4 * 4 + 2][sr] = rb1[it].z; B1s[nxt][c4 * 4 + 3][sr] = rb1[it].w;
                    B3s[nxt][c4 * 4 + 0][sr] = rb3[it].x; B3s[nxt][c4 * 4 + 1][sr] = rb3[it].y;
                    B3s[nxt][c4 * 4 + 2][sr] = rb3[it].z; B3s[nxt][c4 * 4 + 3][sr] = rb3[it].w;
                }
            }
            __syncthreads();
        }

#pragma unroll
        for (int i = 0; i < 8; ++i) {
            int m = ty * 8 + i;
            if (tb + m < nt) {
                int sl = slots[m];
                float4 o;
                float h1, h3v;
                h1 = c1[i][0]; h3v = c3[i][0]; o.x = (h1 / (1.f + expf(-h1))) * h3v;
                h1 = c1[i][1]; h3v = c3[i][1]; o.y = (h1 / (1.f + expf(-h1))) * h3v;
                h1 = c1[i][2]; h3v = c3[i][2]; o.z = (h1 / (1.f + expf(-h1))) * h3v;
                h1 = c1[i][3]; h3v = c3[i][3]; o.w = (h1 / (1.f + expf(-h1))) * h3v;
                *(float4*)(abuf + (size_t)sl * I_ + i0 + tx * 4) = o;
            }
        }
        __syncthreads();
    }
}

// ---------------------------------------------------------------- MoE down: routed[t,:] += gw * a[slot,:] @ w2[e]^T
// 128 threads, BM=64 slots, BN=64 of D, BK=32, per-thread 8x4, double-buffered.
__global__ __launch_bounds__(128) void moe_down_kernel(const float* __restrict__ abuf,
                                                       const float* __restrict__ w2,
                                                       const int* __restrict__ counts,
                                                       const int* __restrict__ elist,
                                                       const float* __restrict__ gw,
                                                       float* __restrict__ routed) {
    const int e = blockIdx.x;
    const int nt = counts[e];
    if (nt == 0) return;
    const int d0 = blockIdx.y * 64;
    const float* W2 = w2 + (size_t)e * D * I_;   // [d][i]
    __shared__ float As[2][32][64], Bs[2][32][64];
    __shared__ int slots[64];
    __shared__ const float* rows[64];
    const int tid = threadIdx.x;
    const int ty = tid >> 4, tx = tid & 15;
    const int sr  = tid & 63;
    const int sc0 = tid >> 6;
    const float* Brow = W2 + (size_t)(d0 + sr) * I_;

    for (int tb = 0; tb < nt; tb += 64) {
        if (tid < 64) {
            int sl = (tb + tid < nt) ? elist[e * T + tb + tid] : -1;
            slots[tid] = sl;
            rows[tid] = (sl >= 0) ? (abuf + (size_t)sl * I_) : nullptr;
        }
        __syncthreads();
        const float* Arow = rows[sr];
        float c[8][4] = {};
        float4 ra[4], rb[4];
#pragma unroll
        for (int it = 0; it < 4; ++it) {
            int c4 = sc0 + 2 * it;
            ra[it] = Arow ? *(const float4*)(Arow + c4 * 4) : make_float4(0.f, 0.f, 0.f, 0.f);
            rb[it] = *(const float4*)(Brow + c4 * 4);
        }
#pragma unroll
        for (int it = 0; it < 4; ++it) {
            int c4 = sc0 + 2 * it;
            As[0][c4 * 4 + 0][sr] = ra[it].x; As[0][c4 * 4 + 1][sr] = ra[it].y;
            As[0][c4 * 4 + 2][sr] = ra[it].z; As[0][c4 * 4 + 3][sr] = ra[it].w;
            Bs[0][c4 * 4 + 0][sr] = rb[it].x; Bs[0][c4 * 4 + 1][sr] = rb[it].y;
            Bs[0][c4 * 4 + 2][sr] = rb[it].z; Bs[0][c4 * 4 + 3][sr] = rb[it].w;
        }
        __syncthreads();

        const int KT = I_ >> 5;   // 16
        for (int kt = 0; kt < KT; ++kt) {
            const int cur = kt & 1;
            if (kt + 1 < KT) {
                const int k0 = (kt + 1) * 32;
#pragma unroll
                for (int it = 0; it < 4; ++it) {
                    int c4 = sc0 + 2 * it;
                    ra[it] = Arow ? *(const float4*)(Arow + k0 + c4 * 4) : make_float4(0.f, 0.f, 0.f, 0.f);
                    rb[it] = *(const float4*)(Brow + k0 + c4 * 4);
                }
            }
#pragma unroll
            for (int kk = 0; kk < 32; ++kk) {
                float4 a0 = *(const float4*)&As[cur][kk][ty * 8];
                float4 a1 = *(const float4*)&As[cur][kk][ty * 8 + 4];
                float4 b0 = *(const float4*)&Bs[cur][kk][tx * 4];
                float a[8] = {a0.x, a0.y, a0.z, a0.w, a1.x, a1.y, a1.z, a1.w};
                float b[4] = {b0.x, b0.y, b0.z, b0.w};
#pragma unroll
                for (int i = 0; i < 8; ++i)
#pragma unroll
                    for (int j = 0; j < 4; ++j) c[i][j] = fmaf(a[i], b[j], c[i][j]);
            }
            if (kt + 1 < KT) {
                const int nxt = cur ^ 1;
#pragma unroll
                for (int it = 0; it < 4; ++it) {
                    int c4 = sc0 + 2 * it;
                    As[nxt][c4 * 4 + 0][sr] = ra[it].x; As[nxt][c4 * 4 + 1][sr] = ra[it].y;
                    As[nxt][c4 * 4 + 2][sr] = ra[it].z; As[nxt][c4 * 4 + 3][sr] = ra[it].w;
                    Bs[nxt][c4 * 4 + 0][sr] = rb[it].x; Bs[nxt][c4 * 4 + 1][sr] = rb[it].y;
                    Bs[nxt][c4 * 4 + 2][sr] = rb[it].z; Bs[nxt][c4 * 4 + 3][sr] = rb[it].w;
                }
            }
            __syncthreads();
        }

#pragma unroll
        for (int i = 0; i < 8; ++i) {
            int m = ty * 8 + i;
            if (tb + m < nt) {
                int sl = slots[m];
                float g = gw[sl];
                int t = sl / TK;
#pragma unroll
                for (int j = 0; j < 4; ++j)
                    atomicAdd(&routed[(size_t)t * D + d0 + tx * 4 + j], g * c[i][j]);
            }
        }
        __syncthreads();
    }
}

// ---------------------------------------------------------------- elementwise
__global__ __launch_bounds__(256) void silu_mul_kernel(const float* __restrict__ a,
                                                       const float* __restrict__ b,
                                                       float* __restrict__ o, int n) {
    int i = blockIdx.x * 256 + threadIdx.x;
    if (i < n) { float x = a[i]; o[i] = x / (1.f + expf(-x)) * b[i]; }
}

__global__ __launch_bounds__(256) void add_inplace_kernel(float* __restrict__ o,
                                                          const float* __restrict__ a, int n) {
    int i = blockIdx.x * 256 + threadIdx.x;
    if (i < n) o[i] += a[i];
}

// ---------------------------------------------------------------- launch
extern "C" void kernel_launch(void* const* d_in, const int* in_sizes, int n_in,
                              void* d_out, int out_size, void* d_ws, size_t ws_size,
                              hipStream_t stream) {
    (void)in_sizes; (void)n_in; (void)out_size; (void)ws_size;
    const float* x      = (const float*)d_in[0];
    const float* fc     = (const float*)d_in[1];
    const float* fs     = (const float*)d_in[2];
    // d_in[3] mask: causality handled analytically
    const float* anw    = (const float*)d_in[4];
    const float* fnw    = (const float*)d_in[5];
    const float* wq     = (const float*)d_in[6];
    const float* wk     = (const float*)d_in[7];
    const float* wv     = (const float*)d_in[8];
    const float* wo     = (const float*)d_in[9];
    const float* gate_w = (const float*)d_in[10];
    const float* ew1    = (const float*)d_in[11];
    const float* ew2    = (const float*)d_in[12];
    const float* ew3    = (const float*)d_in[13];
    const float* sw1    = (const float*)d_in[14];
    const float* sw2    = (const float*)d_in[15];
    const float* sw3    = (const float*)d_in[16];
    float* out = (float*)d_out;

    char* wsp = (char*)d_ws;
    size_t off = 0;
    auto alloc = [&](size_t bytes) {
        void* p = wsp + off;
        off += (bytes + 255) & ~(size_t)255;
        return p;
    };
    float* hbuf   = (float*)alloc((size_t)T * D * 4);
    float* qbuf   = (float*)alloc((size_t)T * D * 4);
    float* kbuf   = (float*)alloc((size_t)T * D * 4);
    float* vbuf   = (float*)alloc((size_t)T * D * 4);
    float* attnb  = (float*)alloc((size_t)T * D * 4);
    float* x1     = (float*)alloc((size_t)T * D * 4);
    float* tbuf   = (float*)alloc((size_t)T * D * 4);
    float* routed = (float*)alloc((size_t)T * D * 4);
    float* logits = (float*)alloc((size_t)T * E * 4);
    float* gwbuf  = (float*)alloc((size_t)T * TK * 4);
    int*   counts = (int*)alloc(E * 4);
    int*   elist  = (int*)alloc((size_t)E * T * 4);
    float* abuf   = (float*)alloc((size_t)T * TK * I_ * 4);
    float* u1     = (float*)alloc((size_t)T * SH_I * 4);
    float* u3     = (float*)alloc((size_t)T * SH_I * 4);
    float* ub     = (float*)alloc((size_t)T * SH_I * 4);

    hipMemsetAsync(counts, 0, E * 4, stream);
    hipMemsetAsync(routed, 0, (size_t)T * D * 4, stream);

    // attention branch
    rmsnorm_kernel<<<T, 256, 0, stream>>>(x, anw, hbuf);
    // fused QKV: z selects weight/output
    gemm_nt_kernel<<<dim3(D / 64, T / 64, 3), 128, 0, stream>>>(hbuf, wq, wk, wv,
                                                                qbuf, kbuf, vbuf,
                                                                nullptr, T, D, D);
    rope_kernel<<<(T * H * HD / 2) / 256, 256, 0, stream>>>(qbuf, kbuf, fc, fs);
    attn_kernel<<<dim3(S, H), 256, 0, stream>>>(qbuf, kbuf, vbuf, attnb);
    gemm_nt_kernel<<<dim3(D / 64, T / 64, 1), 128, 0, stream>>>(attnb, wo, wo, wo,
                                                                x1, x1, x1,
                                                                x, T, D, D);

    // FFN branch
    rmsnorm_kernel<<<T, 256, 0, stream>>>(x1, fnw, tbuf);
    gate_kernel<<<T, 256, 0, stream>>>(tbuf, gate_w, logits);
    routing_kernel<<<T, 64, 0, stream>>>(logits, gwbuf, counts, elist);
    moe_up_kernel<<<dim3(E, I_ / 64), 128, 0, stream>>>(tbuf, ew1, ew3, counts, elist, abuf);
    moe_down_kernel<<<dim3(E, D / 64), 128, 0, stream>>>(abuf, ew2, counts, elist, gwbuf, routed);

    // shared expert: sw1/sw3 fused via z
    gemm_nt_kernel<<<dim3(SH_I / 64, T / 64, 2), 128, 0, stream>>>(tbuf, sw1, sw3, sw3,
                                                                   u1, u3, u3,
                                                                   nullptr, T, SH_I, D);
    silu_mul_kernel<<<(T * SH_I) / 256, 256, 0, stream>>>(u1, u3, ub, T * SH_I);
    gemm_nt_kernel<<<dim3(D / 64, T / 64, 1), 128, 0, stream>>>(ub, sw2, sw2, sw2,
                                                                out, out, out,
                                                                x1, T, D, SH_I);
    add_inplace_kernel<<<(T * D) / 256, 256, 0, stream>>>(out, routed, T * D);
}

// Round 2
// 2298.005 us; speedup vs baseline: 1.3760x; 1.1782x over previous
//
#include <hip/hip_runtime.h>
#include <hip/hip_bf16.h>
#include <math.h>

// Problem constants (from reference)
constexpr int S   = 512;
constexpr int D   = 2048;
constexpr int H   = 16;
constexpr int HD  = 128;
constexpr int T   = 512;     // B*S
constexpr int E   = 64;
constexpr int I_  = 512;
constexpr int G   = 8;
constexpr int TKG = 4;
constexpr int TK  = 6;
constexpr int SH_I = 1024;
constexpr float ROUTE_SCALE = 2.5f;
constexpr float EPS = 1e-5f;

// ---------------------------------------------------------------- rmsnorm
__global__ __launch_bounds__(256) void rmsnorm_kernel(const float* __restrict__ x,
                                                      const float* __restrict__ w,
                                                      float* __restrict__ out) {
    int t = blockIdx.x;
    int tid = threadIdx.x;
    const float* row = x + (size_t)t * D;
    float ss = 0.f;
    for (int i = tid; i < D; i += 256) { float v = row[i]; ss += v * v; }
    for (int o = 32; o; o >>= 1) ss += __shfl_down(ss, o, 64);
    __shared__ float red[4];
    if ((tid & 63) == 0) red[tid >> 6] = ss;
    __syncthreads();
    float tot = red[0] + red[1] + red[2] + red[3];
    float scale = rsqrtf(tot / (float)D + EPS);
    for (int i = tid; i < D; i += 256) out[(size_t)t * D + i] = row[i] * scale * w[i];
}

// ---------------------------------------------------------------- GEMM: C = A(MxK) @ B(NxK)^T (+ addsrc)
// 512 threads = 4 k-split groups of 128. Each group computes the full 64x64
// tile over K/4, then LDS-reduce into group 0. Single-buffered per-group LDS
// with register prefetch of the next k-slice. blockIdx.z selects (B,C).
// Requires M%64==0, N%64==0, K%64==0.
__global__ __launch_bounds__(512) void gemm_nt_kernel(const float* __restrict__ A,
                                                      const float* __restrict__ B0,
                                                      const float* __restrict__ B1,
                                                      const float* __restrict__ B2,
                                                      float* __restrict__ C0,
                                                      float* __restrict__ C1,
                                                      float* __restrict__ C2,
                                                      const float* __restrict__ addsrc,
                                                      int M, int N, int K) {
    const float* B = (blockIdx.z == 0) ? B0 : ((blockIdx.z == 1) ? B1 : B2);
    float*       C = (blockIdx.z == 0) ? C0 : ((blockIdx.z == 1) ? C1 : C2);
    __shared__ float As[4][16][64];   // per-group k-major tiles; also reused as 64x64 reduce buf
    __shared__ float Bs[4][16][64];
    const int m0 = blockIdx.y * 64, n0 = blockIdx.x * 64;
    const int tid = threadIdx.x;
    const int g   = tid >> 7;         // k-split group 0..3
    const int l   = tid & 127;
    const int ty  = l >> 4;           // 0..7
    const int tx  = l & 15;           // 0..15
    const int srow = l & 63;
    const int sk0  = (l >> 6) * 8;    // 0 or 8
    const int Kq = K >> 2;
    const float* Arow = A + (size_t)(m0 + srow) * K + g * Kq + sk0;
    const float* Brow = B + (size_t)(n0 + srow) * K + g * Kq + sk0;

    float c[8][4] = {};
    const int KT = Kq >> 4;
    float4 ra0 = *(const float4*)(Arow);
    float4 ra1 = *(const float4*)(Arow + 4);
    float4 rb0 = *(const float4*)(Brow);
    float4 rb1 = *(const float4*)(Brow + 4);

    for (int kt = 0; kt < KT; ++kt) {
        __syncthreads();   // previous tile fully consumed
        As[g][sk0 + 0][srow] = ra0.x; As[g][sk0 + 1][srow] = ra0.y;
        As[g][sk0 + 2][srow] = ra0.z; As[g][sk0 + 3][srow] = ra0.w;
        As[g][sk0 + 4][srow] = ra1.x; As[g][sk0 + 5][srow] = ra1.y;
        As[g][sk0 + 6][srow] = ra1.z; As[g][sk0 + 7][srow] = ra1.w;
        Bs[g][sk0 + 0][srow] = rb0.x; Bs[g][sk0 + 1][srow] = rb0.y;
        Bs[g][sk0 + 2][srow] = rb0.z; Bs[g][sk0 + 3][srow] = rb0.w;
        Bs[g][sk0 + 4][srow] = rb1.x; Bs[g][sk0 + 5][srow] = rb1.y;
        Bs[g][sk0 + 6][srow] = rb1.z; Bs[g][sk0 + 7][srow] = rb1.w;
        __syncthreads();
        if (kt + 1 < KT) {           // prefetch next slice; vmcnt-wait lands at next write phase
            ra0 = *(const float4*)(Arow + (kt + 1) * 16);
            ra1 = *(const float4*)(Arow + (kt + 1) * 16 + 4);
            rb0 = *(const float4*)(Brow + (kt + 1) * 16);
            rb1 = *(const float4*)(Brow + (kt + 1) * 16 + 4);
        }
#pragma unroll
        for (int kk = 0; kk < 16; ++kk) {
            float4 a0 = *(const float4*)&As[g][kk][ty * 8];
            float4 a1 = *(const float4*)&As[g][kk][ty * 8 + 4];
            float4 b0 = *(const float4*)&Bs[g][kk][tx * 4];
            float a[8] = {a0.x, a0.y, a0.z, a0.w, a1.x, a1.y, a1.z, a1.w};
            float b[4] = {b0.x, b0.y, b0.z, b0.w};
#pragma unroll
            for (int i = 0; i < 8; ++i)
#pragma unroll
                for (int j = 0; j < 4; ++j) c[i][j] = fmaf(a[i], b[j], c[i][j]);
        }
    }

    // k-split reduction into group 0 (reuse As as 64x64 f32 buffer = 16 KB)
    __syncthreads();
    float* cred = &As[0][0][0];
#pragma unroll 1
    for (int gg = 1; gg < 4; ++gg) {
        if (g == gg) {
#pragma unroll
            for (int i = 0; i < 8; ++i) {
                float4 v; v.x = c[i][0]; v.y = c[i][1]; v.z = c[i][2]; v.w = c[i][3];
                *(float4*)&cred[(ty * 8 + i) * 64 + tx * 4] = v;
            }
        }
        __syncthreads();
        if (g == 0) {
#pragma unroll
            for (int i = 0; i < 8; ++i) {
                float4 v = *(const float4*)&cred[(ty * 8 + i) * 64 + tx * 4];
                c[i][0] += v.x; c[i][1] += v.y; c[i][2] += v.z; c[i][3] += v.w;
            }
        }
        __syncthreads();
    }

    if (g == 0) {
#pragma unroll
        for (int i = 0; i < 8; ++i) {
            size_t off = (size_t)(m0 + ty * 8 + i) * N + n0 + tx * 4;
            float4 o; o.x = c[i][0]; o.y = c[i][1]; o.z = c[i][2]; o.w = c[i][3];
            if (addsrc) {
                float4 ad = *(const float4*)(addsrc + off);
                o.x += ad.x; o.y += ad.y; o.z += ad.z; o.w += ad.w;
            }
            *(float4*)(C + off) = o;
        }
    }
}

// ---------------------------------------------------------------- RoPE (in-place on q and k)
__global__ __launch_bounds__(256) void rope_kernel(float* __restrict__ q, float* __restrict__ k,
                                                   const float* __restrict__ fc,
                                                   const float* __restrict__ fs) {
    int idx = blockIdx.x * 256 + threadIdx.x;   // T*H*(HD/2)
    int p  = idx & (HD / 2 - 1);
    int hh = (idx >> 6) & (H - 1);
    int t  = idx >> 10;
    float c = fc[t * (HD / 2) + p], s = fs[t * (HD / 2) + p];
    size_t base = (size_t)t * D + hh * HD + p * 2;
    float re = q[base], im = q[base + 1];
    q[base]     = re * c - im * s;
    q[base + 1] = re * s + im * c;
    re = k[base]; im = k[base + 1];
    k[base]     = re * c - im * s;
    k[base + 1] = re * s + im * c;
}

// ---------------------------------------------------------------- attention: one block per (q-row, head)
__global__ __launch_bounds__(256) void attn_kernel(const float* __restrict__ q,
                                                   const float* __restrict__ k,
                                                   const float* __restrict__ v,
                                                   float* __restrict__ o) {
    int qi = blockIdx.x, hh = blockIdx.y, tid = threadIdx.x;
    __shared__ float qs[HD];
    __shared__ float sc[S];
    __shared__ float redm[4];
    __shared__ float redz[4];
    __shared__ float part[256];
    if (tid < HD) qs[tid] = q[(size_t)qi * D + hh * HD + tid];
    __syncthreads();
    int kn = qi + 1;            // causal
    float lmax = -1e30f;
    for (int kk = tid; kk < kn; kk += 256) {
        const float4* k4 = (const float4*)(k + (size_t)kk * D + hh * HD);
        const float4* q4 = (const float4*)qs;
        float s = 0.f;
#pragma unroll
        for (int d4 = 0; d4 < HD / 4; d4++) {
            float4 kvv = k4[d4], qvv = q4[d4];
            s += qvv.x * kvv.x + qvv.y * kvv.y + qvv.z * kvv.z + qvv.w * kvv.w;
        }
        s *= 0.08838834764831845f;   // 1/sqrt(128)
        sc[kk] = s;
        lmax = fmaxf(lmax, s);
    }
    for (int o2 = 32; o2; o2 >>= 1) lmax = fmaxf(lmax, __shfl_down(lmax, o2, 64));
    if ((tid & 63) == 0) redm[tid >> 6] = lmax;
    __syncthreads();
    float M_ = fmaxf(fmaxf(redm[0], redm[1]), fmaxf(redm[2], redm[3]));
    float lsum = 0.f;
    for (int kk = tid; kk < kn; kk += 256) {
        float e2 = expf(sc[kk] - M_);
        sc[kk] = e2;
        lsum += e2;
    }
    for (int o2 = 32; o2; o2 >>= 1) lsum += __shfl_down(lsum, o2, 64);
    if ((tid & 63) == 0) redz[tid >> 6] = lsum;
    __syncthreads();
    float Z = redz[0] + redz[1] + redz[2] + redz[3];
    int d2 = tid & (HD - 1);
    int halfsel = tid >> 7;
    float acc = 0.f;
    for (int kk = halfsel; kk < kn; kk += 2)
        acc += sc[kk] * v[(size_t)kk * D + hh * HD + d2];
    part[tid] = acc;
    __syncthreads();
    if (tid < HD) o[(size_t)qi * D + hh * HD + tid] = (part[tid] + part[tid + HD]) / Z;
}

// ---------------------------------------------------------------- gate logits: one block per token (skinny N=64)
__global__ __launch_bounds__(256) void gate_kernel(const float* __restrict__ tbuf,
                                                   const float* __restrict__ gate_w,
                                                   float* __restrict__ logits) {
    int tok = blockIdx.x;
    int e    = threadIdx.x >> 2;   // 0..63
    int part = threadIdx.x & 3;    // 0..3
    const float* trow = tbuf   + (size_t)tok * D;
    const float* wrow = gate_w + (size_t)e * D;
    float s = 0.f;
    for (int k = part * 4; k < D; k += 16) {
        float4 a = *(const float4*)(trow + k);
        float4 b = *(const float4*)(wrow + k);
        s += a.x * b.x + a.y * b.y + a.z * b.z + a.w * b.w;
    }
    s += __shfl_down(s, 1, 4);
    s += __shfl_down(s, 2, 4);
    if (part == 0) logits[(size_t)tok * E + e] = s;
}

// ---------------------------------------------------------------- routing (sigmoid gate + group top-k + expert top-k)
__global__ __launch_bounds__(64) void routing_kernel(const float* __restrict__ logits,
                                                     float* __restrict__ gw,
                                                     int* __restrict__ counts,
                                                     int* __restrict__ elist) {
    int t = blockIdx.x;
    int lane = threadIdx.x;
    __shared__ float ss[E];
    if (lane < E) ss[lane] = 1.f / (1.f + expf(-logits[(size_t)t * E + lane]));
    __syncthreads();
    if (lane == 0) {
        float gs[G];
        for (int g = 0; g < G; g++) {
            float m = ss[g * 8];
            for (int j = 1; j < 8; j++) m = fmaxf(m, ss[g * 8 + j]);
            gs[g] = m;
        }
        bool keep[G];
        for (int g = 0; g < G; g++) keep[g] = false;
        for (int r = 0; r < TKG; r++) {
            int best = -1; float bv = -1e30f;
            for (int g = 0; g < G; g++)
                if (!keep[g] && gs[g] > bv) { bv = gs[g]; best = g; }
            keep[best] = true;
        }
        float masked[E];
        for (int e2 = 0; e2 < E; e2++) masked[e2] = keep[e2 >> 3] ? ss[e2] : -1e30f;
        int chosen[TK]; float w[TK]; float wsum = 0.f;
        for (int r = 0; r < TK; r++) {
            int best = 0; float bv = -1e31f;
            for (int e2 = 0; e2 < E; e2++)
                if (masked[e2] > bv) { bv = masked[e2]; best = e2; }
            chosen[r] = best; w[r] = ss[best]; masked[best] = -1e31f; wsum += w[r];
        }
        float scale_ = ROUTE_SCALE / wsum;
        for (int r = 0; r < TK; r++) {
            int slot = t * TK + r;
            gw[slot] = w[r] * scale_;
            int e2 = chosen[r];
            int pos = atomicAdd(&counts[e2], 1);
            elist[e2 * T + pos] = slot;
        }
    }
}

// ---------------------------------------------------------------- MoE up: a[slot, i] = silu(t@w1^T) * (t@w3^T)
// 512 threads = 4 k-split groups of 128, BM=64 slots, BN=64 of I.
// Same structure as gemm_nt with two B matrices and fused silu epilogue.
__global__ __launch_bounds__(512) void moe_up_kernel(const float* __restrict__ tbuf,
                                                     const float* __restrict__ w1,
                                                     const float* __restrict__ w3,
                                                     const int* __restrict__ counts,
                                                     const int* __restrict__ elist,
                                                     float* __restrict__ abuf) {
    const int e = blockIdx.x;
    const int nt = counts[e];
    if (nt == 0) return;
    const int i0 = blockIdx.y * 64;
    const float* W1 = w1 + (size_t)e * I_ * D;
    const float* W3 = w3 + (size_t)e * I_ * D;
    __shared__ float As[4][16][64];    // also reused as reduce buf for c1
    __shared__ float B1s[4][16][64];   // also reused as reduce buf for c3
    __shared__ float B3s[4][16][64];
    __shared__ int slots[64];
    __shared__ const float* rows[64];
    const int tid = threadIdx.x;
    const int g   = tid >> 7;
    const int l   = tid & 127;
    const int ty  = l >> 4, tx = l & 15;
    const int srow = l & 63;
    const int sk0  = (l >> 6) * 8;
    const int Kq = D >> 2;             // 512
    const int KT = Kq >> 4;            // 32
    const float* B1row = W1 + (size_t)(i0 + srow) * D + g * Kq + sk0;
    const float* B3row = W3 + (size_t)(i0 + srow) * D + g * Kq + sk0;

    for (int tb = 0; tb < nt; tb += 64) {
        if (tid < 64) {
            int sl = (tb + tid < nt) ? elist[e * T + tb + tid] : -1;
            slots[tid] = sl;
            rows[tid] = (sl >= 0) ? (tbuf + (size_t)(sl / TK) * D + g * 0) : nullptr;
        }
        __syncthreads();
        const float* Arow = rows[srow];
        const float* Ap = Arow ? (Arow + g * Kq + sk0) : nullptr;
        float c1[8][4] = {}, c3[8][4] = {};
        float4 ra0, ra1, rb10, rb11, rb30, rb31;
        const float4 z4 = make_float4(0.f, 0.f, 0.f, 0.f);
        ra0  = Ap ? *(const float4*)(Ap)     : z4;
        ra1  = Ap ? *(const float4*)(Ap + 4) : z4;
        rb10 = *(const float4*)(B1row);
        rb11 = *(const float4*)(B1row + 4);
        rb30 = *(const float4*)(B3row);
        rb31 = *(const float4*)(B3row + 4);

        for (int kt = 0; kt < KT; ++kt) {
            __syncthreads();
            As[g][sk0 + 0][srow] = ra0.x;  As[g][sk0 + 1][srow] = ra0.y;
            As[g][sk0 + 2][srow] = ra0.z;  As[g][sk0 + 3][srow] = ra0.w;
            As[g][sk0 + 4][srow] = ra1.x;  As[g][sk0 + 5][srow] = ra1.y;
            As[g][sk0 + 6][srow] = ra1.z;  As[g][sk0 + 7][srow] = ra1.w;
            B1s[g][sk0 + 0][srow] = rb10.x; B1s[g][sk0 + 1][srow] = rb10.y;
            B1s[g][sk0 + 2][srow] = rb10.z; B1s[g][sk0 + 3][srow] = rb10.w;
            B1s[g][sk0 + 4][srow] = rb11.x; B1s[g][sk0 + 5][srow] = rb11.y;
            B1s[g][sk0 + 6][srow] = rb11.z; B1s[g][sk0 + 7][srow] = rb11.w;
            B3s[g][sk0 + 0][srow] = rb30.x; B3s[g][sk0 + 1][srow] = rb30.y;
            B3s[g][sk0 + 2][srow] = rb30.z; B3s[g][sk0 + 3][srow] = rb30.w;
            B3s[g][sk0 + 4][srow] = rb31.x; B3s[g][sk0 + 5][srow] = rb31.y;
            B3s[g][sk0 + 6][srow] = rb31.z; B3s[g][sk0 + 7][srow] = rb31.w;
            __syncthreads();
            if (kt + 1 < KT) {
                const int ko = (kt + 1) * 16;
                ra0  = Ap ? *(const float4*)(Ap + ko)     : z4;
                ra1  = Ap ? *(const float4*)(Ap + ko + 4) : z4;
                rb10 = *(const float4*)(B1row + ko);
                rb11 = *(const float4*)(B1row + ko + 4);
                rb30 = *(const float4*)(B3row + ko);
                rb31 = *(const float4*)(B3row + ko + 4);
            }
#pragma unroll
            for (int kk = 0; kk < 16; ++kk) {
                float4 a0 = *(const float4*)&As[g][kk][ty * 8];
                float4 a1 = *(const float4*)&As[g][kk][ty * 8 + 4];
                float4 v1 = *(const float4*)&B1s[g][kk][tx * 4];
                float4 v3 = *(const float4*)&B3s[g][kk][tx * 4];
                float a[8]  = {a0.x, a0.y, a0.z, a0.w, a1.x, a1.y, a1.z, a1.w};
                float b1v[4] = {v1.x, v1.y, v1.z, v1.w};
                float b3v[4] = {v3.x, v3.y, v3.z, v3.w};
#pragma unroll
                for (int i = 0; i < 8; ++i) {
#pragma unroll
                    for (int j = 0; j < 4; ++j) {
                        c1[i][j] = fmaf(a[i], b1v[j], c1[i][j]);
                        c3[i][j] = fmaf(a[i], b3v[j], c3[i][j]);
                    }
                }
            }
        }

        // reduce c1 (via As) and c3 (via B1s) into group 0
        __syncthreads();
        float* r1 = &As[0][0][0];
        float* r3 = &B1s[0][0][0];
#pragma unroll 1
        for (int gg = 1; gg < 4; ++gg) {
            if (g == gg) {
#pragma unroll
                for (int i = 0; i < 8; ++i) {
                    float4 v; v.x = c1[i][0]; v.y = c1[i][1]; v.z = c1[i][2]; v.w = c1[i][3];
                    *(float4*)&r1[(ty * 8 + i) * 64 + tx * 4] = v;
                    float4 u; u.x = c3[i][0]; u.y = c3[i][1]; u.z = c3[i][2]; u.w = c3[i][3];
                    *(float4*)&r3[(ty * 8 + i) * 64 + tx * 4] = u;
                }
            }
            __syncthreads();
            if (g == 0) {
#pragma unroll
                for (int i = 0; i < 8; ++i) {
                    float4 v = *(const float4*)&r1[(ty * 8 + i) * 64 + tx * 4];
                    c1[i][0] += v.x; c1[i][1] += v.y; c1[i][2] += v.z; c1[i][3] += v.w;
                    float4 u = *(const float4*)&r3[(ty * 8 + i) * 64 + tx * 4];
                    c3[i][0] += u.x; c3[i][1] += u.y; c3[i][2] += u.z; c3[i][3] += u.w;
                }
            }
            __syncthreads();
        }

        if (g == 0) {
#pragma unroll
            for (int i = 0; i < 8; ++i) {
                int m = ty * 8 + i;
                if (tb + m < nt) {
                    int sl = slots[m];
                    float4 o;
                    float h1, h3v;
                    h1 = c1[i][0]; h3v = c3[i][0]; o.x = (h1 / (1.f + expf(-h1))) * h3v;
                    h1 = c1[i][1]; h3v = c3[i][1]; o.y = (h1 / (1.f + expf(-h1))) * h3v;
                    h1 = c1[i][2]; h3v = c3[i][2]; o.z = (h1 / (1.f + expf(-h1))) * h3v;
                    h1 = c1[i][3]; h3v = c3[i][3]; o.w = (h1 / (1.f + expf(-h1))) * h3v;
                    *(float4*)(abuf + (size_t)sl * I_ + i0 + tx * 4) = o;
                }
            }
        }
        __syncthreads();
    }
}

// ---------------------------------------------------------------- MoE down: routed[t,:] += gw * a[slot,:] @ w2[e]^T
// 128 threads, BM=64 slots, BN=64 of D, BK=32, per-thread 8x4, double-buffered.
__global__ __launch_bounds__(128) void moe_down_kernel(const float* __restrict__ abuf,
                                                       const float* __restrict__ w2,
                                                       const int* __restrict__ counts,
                                                       const int* __restrict__ elist,
                                                       const float* __restrict__ gw,
                                                       float* __restrict__ routed) {
    const int e = blockIdx.x;
    const int nt = counts[e];
    if (nt == 0) return;
    const int d0 = blockIdx.y * 64;
    const float* W2 = w2 + (size_t)e * D * I_;   // [d][i]
    __shared__ float As[2][32][64], Bs[2][32][64];
    __shared__ int slots[64];
    __shared__ const float* rows[64];
    const int tid = threadIdx.x;
    const int ty = tid >> 4, tx = tid & 15;
    const int sr  = tid & 63;
    const int sc0 = tid >> 6;
    const float* Brow = W2 + (size_t)(d0 + sr) * I_;

    for (int tb = 0; tb < nt; tb += 64) {
        if (tid < 64) {
            int sl = (tb + tid < nt) ? elist[e * T + tb + tid] : -1;
            slots[tid] = sl;
            rows[tid] = (sl >= 0) ? (abuf + (size_t)sl * I_) : nullptr;
        }
        __syncthreads();
        const float* Arow = rows[sr];
        float c[8][4] = {};
        float4 ra[4], rb[4];
#pragma unroll
        for (int it = 0; it < 4; ++it) {
            int c4 = sc0 + 2 * it;
            ra[it] = Arow ? *(const float4*)(Arow + c4 * 4) : make_float4(0.f, 0.f, 0.f, 0.f);
            rb[it] = *(const float4*)(Brow + c4 * 4);
        }
#pragma unroll
        for (int it = 0; it < 4; ++it) {
            int c4 = sc0 + 2 * it;
            As[0][c4 * 4 + 0][sr] = ra[it].x; As[0][c4 * 4 + 1][sr] = ra[it].y;
            As[0][c4 * 4 + 2][sr] = ra[it].z; As[0][c4 * 4 + 3][sr] = ra[it].w;
            Bs[0][c4 * 4 + 0][sr] = rb[it].x; Bs[0][c4 * 4 + 1][sr] = rb[it].y;
            Bs[0][c4 * 4 + 2][sr] = rb[it].z; Bs[0][c4 * 4 + 3][sr] = rb[it].w;
        }
        __syncthreads();

        const int KT = I_ >> 5;   // 16
        for (int kt = 0; kt < KT; ++kt) {
            const int cur = kt & 1;
            if (kt + 1 < KT) {
                const int k0 = (kt + 1) * 32;
#pragma unroll
                for (int it = 0; it < 4; ++it) {
                    int c4 = sc0 + 2 * it;
                    ra[it] = Arow ? *(const float4*)(Arow + k0 + c4 * 4) : make_float4(0.f, 0.f, 0.f, 0.f);
                    rb[it] = *(const float4*)(Brow + k0 + c4 * 4);
                }
            }
#pragma unroll
            for (int kk = 0; kk < 32; ++kk) {
                float4 a0 = *(const float4*)&As[cur][kk][ty * 8];
                float4 a1 = *(const float4*)&As[cur][kk][ty * 8 + 4];
                float4 b0 = *(const float4*)&Bs[cur][kk][tx * 4];
                float a[8] = {a0.x, a0.y, a0.z, a0.w, a1.x, a1.y, a1.z, a1.w};
                float b[4] = {b0.x, b0.y, b0.z, b0.w};
#pragma unroll
                for (int i = 0; i < 8; ++i)
#pragma unroll
                    for (int j = 0; j < 4; ++j) c[i][j] = fmaf(a[i], b[j], c[i][j]);
            }
            if (kt + 1 < KT) {
                const int nxt = cur ^ 1;
#pragma unroll
                for (int it = 0; it < 4; ++it) {
                    int c4 = sc0 + 2 * it;
                    As[nxt][c4 * 4 + 0][sr] = ra[it].x; As[nxt][c4 * 4 + 1][sr] = ra[it].y;
                    As[nxt][c4 * 4 + 2][sr] = ra[it].z; As[nxt][c4 * 4 + 3][sr] = ra[it].w;
                    Bs[nxt][c4 * 4 + 0][sr] = rb[it].x; Bs[nxt][c4 * 4 + 1][sr] = rb[it].y;
                    Bs[nxt][c4 * 4 + 2][sr] = rb[it].z; Bs[nxt][c4 * 4 + 3][sr] = rb[it].w;
                }
            }
            __syncthreads();
        }

#pragma unroll
        for (int i = 0; i < 8; ++i) {
            int m = ty * 8 + i;
            if (tb + m < nt) {
                int sl = slots[m];
                float g = gw[sl];
                int t = sl / TK;
#pragma unroll
                for (int j = 0; j < 4; ++j)
                    atomicAdd(&routed[(size_t)t * D + d0 + tx * 4 + j], g * c[i][j]);
            }
        }
        __syncthreads();
    }
}

// ---------------------------------------------------------------- elementwise
__global__ __launch_bounds__(256) void silu_mul_kernel(const float* __restrict__ a,
                                                       const float* __restrict__ b,
                                                       float* __restrict__ o, int n) {
    int i = blockIdx.x * 256 + threadIdx.x;
    if (i < n) { float x = a[i]; o[i] = x / (1.f + expf(-x)) * b[i]; }
}

__global__ __launch_bounds__(256) void add_inplace_kernel(float* __restrict__ o,
                                                          const float* __restrict__ a, int n) {
    int i = blockIdx.x * 256 + threadIdx.x;
    if (i < n) o[i] += a[i];
}

// ---------------------------------------------------------------- launch
extern "C" void kernel_launch(void* const* d_in, const int* in_sizes, int n_in,
                              void* d_out, int out_size, void* d_ws, size_t ws_size,
                              hipStream_t stream) {
    (void)in_sizes; (void)n_in; (void)out_size; (void)ws_size;
    const float* x      = (const float*)d_in[0];
    const float* fc     = (const float*)d_in[1];
    const float* fs     = (const float*)d_in[2];
    // d_in[3] mask: causality handled analytically
    const float* anw    = (const float*)d_in[4];
    const float* fnw    = (const float*)d_in[5];
    const float* wq     = (const float*)d_in[6];
    const float* wk     = (const float*)d_in[7];
    const float* wv     = (const float*)d_in[8];
    const float* wo     = (const float*)d_in[9];
    const float* gate_w = (const float*)d_in[10];
    const float* ew1    = (const float*)d_in[11];
    const float* ew2    = (const float*)d_in[12];
    const float* ew3    = (const float*)d_in[13];
    const float* sw1    = (const float*)d_in[14];
    const float* sw2    = (const float*)d_in[15];
    const float* sw3    = (const float*)d_in[16];
    float* out = (float*)d_out;

    char* wsp = (char*)d_ws;
    size_t off = 0;
    auto alloc = [&](size_t bytes) {
        void* p = wsp + off;
        off += (bytes + 255) & ~(size_t)255;
        return p;
    };
    float* hbuf   = (float*)alloc((size_t)T * D * 4);
    float* qbuf   = (float*)alloc((size_t)T * D * 4);
    float* kbuf   = (float*)alloc((size_t)T * D * 4);
    float* vbuf   = (float*)alloc((size_t)T * D * 4);
    float* attnb  = (float*)alloc((size_t)T * D * 4);
    float* x1     = (float*)alloc((size_t)T * D * 4);
    float* tbuf   = (float*)alloc((size_t)T * D * 4);
    float* routed = (float*)alloc((size_t)T * D * 4);
    float* logits = (float*)alloc((size_t)T * E * 4);
    float* gwbuf  = (float*)alloc((size_t)T * TK * 4);
    int*   counts = (int*)alloc(E * 4);
    int*   elist  = (int*)alloc((size_t)E * T * 4);
    float* abuf   = (float*)alloc((size_t)T * TK * I_ * 4);
    float* u1     = (float*)alloc((size_t)T * SH_I * 4);
    float* u3     = (float*)alloc((size_t)T * SH_I * 4);
    float* ub     = (float*)alloc((size_t)T * SH_I * 4);

    hipMemsetAsync(counts, 0, E * 4, stream);
    hipMemsetAsync(routed, 0, (size_t)T * D * 4, stream);

    // attention branch
    rmsnorm_kernel<<<T, 256, 0, stream>>>(x, anw, hbuf);
    // fused QKV: z selects weight/output
    gemm_nt_kernel<<<dim3(D / 64, T / 64, 3), 512, 0, stream>>>(hbuf, wq, wk, wv,
                                                                qbuf, kbuf, vbuf,
                                                                nullptr, T, D, D);
    rope_kernel<<<(T * H * HD / 2) / 256, 256, 0, stream>>>(qbuf, kbuf, fc, fs);
    attn_kernel<<<dim3(S, H), 256, 0, stream>>>(qbuf, kbuf, vbuf, attnb);
    gemm_nt_kernel<<<dim3(D / 64, T / 64, 1), 512, 0, stream>>>(attnb, wo, wo, wo,
                                                                x1, x1, x1,
                                                                x, T, D, D);

    // FFN branch
    rmsnorm_kernel<<<T, 256, 0, stream>>>(x1, fnw, tbuf);
    gate_kernel<<<T, 256, 0, stream>>>(tbuf, gate_w, logits);
    routing_kernel<<<T, 64, 0, stream>>>(logits, gwbuf, counts, elist);
    moe_up_kernel<<<dim3(E, I_ / 64), 512, 0, stream>>>(tbuf, ew1, ew3, counts, elist, abuf);
    moe_down_kernel<<<dim3(E, D / 64), 128, 0, stream>>>(abuf, ew2, counts, elist, gwbuf, routed);

    // shared expert: sw1/sw3 fused via z
    gemm_nt_kernel<<<dim3(SH_I / 64, T / 64, 2), 512, 0, stream>>>(tbuf, sw1, sw3, sw3,
                                                                   u1, u3, u3,
                                                                   nullptr, T, SH_I, D);
    silu_mul_kernel<<<(T * SH_I) / 256, 256, 0, stream>>>(u1, u3, ub, T * SH_I);
    gemm_nt_kernel<<<dim3(D / 64, T / 64, 1), 512, 0, stream>>>(ub, sw2, sw2, sw2,
                                                                out, out, out,
                                                                x1, T, D, SH_I);
    add_inplace_kernel<<<(T * D) / 256, 256, 0, stream>>>(out, routed, T * D);
}

// Round 3
// 1677.628 us; speedup vs baseline: 1.8848x; 1.3698x over previous
//
#include <hip/hip_runtime.h>
#include <hip/hip_bf16.h>
#include <math.h>

// Problem constants (from reference)
constexpr int S   = 512;
constexpr int D   = 2048;
constexpr int H   = 16;
constexpr int HD  = 128;
constexpr int T   = 512;     // B*S
constexpr int E   = 64;
constexpr int I_  = 512;
constexpr int G   = 8;
constexpr int TKG = 4;
constexpr int TK  = 6;
constexpr int SH_I = 1024;
constexpr float ROUTE_SCALE = 2.5f;
constexpr float EPS = 1e-5f;

typedef short   s16x8   __attribute__((ext_vector_type(8)));
typedef unsigned short ushort8 __attribute__((ext_vector_type(8)));
typedef float   f32x4   __attribute__((ext_vector_type(4)));

// split fp32 -> (hi, lo) bf16 bit patterns; hi RNE, lo = bf16(x - hi)
__device__ inline void split8(const float4& x0, const float4& x1, ushort8& h, ushort8& l) {
    float xs[8] = {x0.x, x0.y, x0.z, x0.w, x1.x, x1.y, x1.z, x1.w};
#pragma unroll
    for (int j = 0; j < 8; ++j) {
        __bf16 hb = (__bf16)xs[j];
        float hf = (float)hb;
        __bf16 lb = (__bf16)(xs[j] - hf);
        h[j] = __builtin_bit_cast(unsigned short, hb);
        l[j] = __builtin_bit_cast(unsigned short, lb);
    }
}

__device__ inline s16x8 ldsfrag(const unsigned short* p) {
    return *(const s16x8*)p;
}

// ---------------------------------------------------------------- rmsnorm
__global__ __launch_bounds__(256) void rmsnorm_kernel(const float* __restrict__ x,
                                                      const float* __restrict__ w,
                                                      float* __restrict__ out) {
    int t = blockIdx.x;
    int tid = threadIdx.x;
    const float* row = x + (size_t)t * D;
    float ss = 0.f;
    for (int i = tid; i < D; i += 256) { float v = row[i]; ss += v * v; }
    for (int o = 32; o; o >>= 1) ss += __shfl_down(ss, o, 64);
    __shared__ float red[4];
    if ((tid & 63) == 0) red[tid >> 6] = ss;
    __syncthreads();
    float tot = red[0] + red[1] + red[2] + red[3];
    float scale = rsqrtf(tot / (float)D + EPS);
    for (int i = tid; i < D; i += 256) out[(size_t)t * D + i] = row[i] * scale * w[i];
}

// ---------------------------------------------------------------- MFMA GEMM: C = A(MxK) @ B(NxK)^T (+ addsrc)
// 256 threads = 4 waves, tile 64x64, each wave owns 32x32 (2x2 fragments of
// 16x16), BK=32 (one mfma_16x16x32 K-step). fp32 via split-bf16 3-product.
// blockIdx.z selects (B,C). Requires M%64==0, N%64==0, K%32==0.
__global__ __launch_bounds__(256) void mgemm_nt_kernel(const float* __restrict__ A,
                                                       const float* __restrict__ B0,
                                                       const float* __restrict__ B1,
                                                       const float* __restrict__ B2,
                                                       float* __restrict__ C0,
                                                       float* __restrict__ C1,
                                                       float* __restrict__ C2,
                                                       const float* __restrict__ addsrc,
                                                       int M, int N, int K) {
    (void)M;
    const float* B = (blockIdx.z == 0) ? B0 : ((blockIdx.z == 1) ? B1 : B2);
    float*       C = (blockIdx.z == 0) ? C0 : ((blockIdx.z == 1) ? C1 : C2);
    __shared__ unsigned short Ah[64][40], Al[64][40], Bh[64][40], Bl[64][40];
    const int m0 = blockIdx.y * 64, n0 = blockIdx.x * 64;
    const int tid = threadIdx.x;
    const int w = tid >> 6, lane = tid & 63;
    const int srow = tid >> 2;          // staging row 0..63
    const int skq  = (tid & 3) * 8;     // staging k offset 0,8,16,24
    const int wm = (w >> 1) * 32, wn = (w & 1) * 32;
    const int fr = lane >> 4, fc = lane & 15;
    const float* Arow = A + (size_t)(m0 + srow) * K + skq;
    const float* Brow = B + (size_t)(n0 + srow) * K + skq;

    f32x4 acc[2][2] = {};
    const int KT = K >> 5;
    float4 pa0 = *(const float4*)(Arow);
    float4 pa1 = *(const float4*)(Arow + 4);
    float4 pb0 = *(const float4*)(Brow);
    float4 pb1 = *(const float4*)(Brow + 4);

    for (int kt = 0; kt < KT; ++kt) {
        __syncthreads();
        {
            ushort8 h, l;
            split8(pa0, pa1, h, l);
            *(ushort8*)&Ah[srow][skq] = h; *(ushort8*)&Al[srow][skq] = l;
            split8(pb0, pb1, h, l);
            *(ushort8*)&Bh[srow][skq] = h; *(ushort8*)&Bl[srow][skq] = l;
        }
        __syncthreads();
        if (kt + 1 < KT) {
            const float* An = Arow + (kt + 1) * 32;
            const float* Bn = Brow + (kt + 1) * 32;
            pa0 = *(const float4*)(An); pa1 = *(const float4*)(An + 4);
            pb0 = *(const float4*)(Bn); pb1 = *(const float4*)(Bn + 4);
        }
        s16x8 fah[2], fal[2], fbh[2], fbl[2];
#pragma unroll
        for (int mf = 0; mf < 2; ++mf) {
            int r = wm + mf * 16 + fc;
            fah[mf] = ldsfrag(&Ah[r][fr * 8]);
            fal[mf] = ldsfrag(&Al[r][fr * 8]);
        }
#pragma unroll
        for (int nf = 0; nf < 2; ++nf) {
            int r = wn + nf * 16 + fc;
            fbh[nf] = ldsfrag(&Bh[r][fr * 8]);
            fbl[nf] = ldsfrag(&Bl[r][fr * 8]);
        }
#pragma unroll
        for (int mf = 0; mf < 2; ++mf)
#pragma unroll
            for (int nf = 0; nf < 2; ++nf) {
                acc[mf][nf] = __builtin_amdgcn_mfma_f32_16x16x32_bf16(fah[mf], fbh[nf], acc[mf][nf], 0, 0, 0);
                acc[mf][nf] = __builtin_amdgcn_mfma_f32_16x16x32_bf16(fah[mf], fbl[nf], acc[mf][nf], 0, 0, 0);
                acc[mf][nf] = __builtin_amdgcn_mfma_f32_16x16x32_bf16(fal[mf], fbh[nf], acc[mf][nf], 0, 0, 0);
            }
    }

#pragma unroll
    for (int mf = 0; mf < 2; ++mf)
#pragma unroll
        for (int nf = 0; nf < 2; ++nf)
#pragma unroll
            for (int r = 0; r < 4; ++r) {
                int gm = m0 + wm + mf * 16 + fr * 4 + r;
                int gn = n0 + wn + nf * 16 + fc;
                size_t off = (size_t)gm * N + gn;
                float v = acc[mf][nf][r];
                if (addsrc) v += addsrc[off];
                C[off] = v;
            }
}

// ---------------------------------------------------------------- RoPE (in-place on q and k)
__global__ __launch_bounds__(256) void rope_kernel(float* __restrict__ q, float* __restrict__ k,
                                                   const float* __restrict__ fc,
                                                   const float* __restrict__ fs) {
    int idx = blockIdx.x * 256 + threadIdx.x;   // T*H*(HD/2)
    int p  = idx & (HD / 2 - 1);
    int hh = (idx >> 6) & (H - 1);
    int t  = idx >> 10;
    float c = fc[t * (HD / 2) + p], s = fs[t * (HD / 2) + p];
    size_t base = (size_t)t * D + hh * HD + p * 2;
    float re = q[base], im = q[base + 1];
    q[base]     = re * c - im * s;
    q[base + 1] = re * s + im * c;
    re = k[base]; im = k[base + 1];
    k[base]     = re * c - im * s;
    k[base + 1] = re * s + im * c;
}

// ---------------------------------------------------------------- attention: one block per (q-row, head)
__global__ __launch_bounds__(256) void attn_kernel(const float* __restrict__ q,
                                                   const float* __restrict__ k,
                                                   const float* __restrict__ v,
                                                   float* __restrict__ o) {
    int qi = blockIdx.x, hh = blockIdx.y, tid = threadIdx.x;
    __shared__ float qs[HD];
    __shared__ float sc[S];
    __shared__ float redm[4];
    __shared__ float redz[4];
    __shared__ float part[256];
    if (tid < HD) qs[tid] = q[(size_t)qi * D + hh * HD + tid];
    __syncthreads();
    int kn = qi + 1;            // causal
    float lmax = -1e30f;
    for (int kk = tid; kk < kn; kk += 256) {
        const float4* k4 = (const float4*)(k + (size_t)kk * D + hh * HD);
        const float4* q4 = (const float4*)qs;
        float s = 0.f;
#pragma unroll
        for (int d4 = 0; d4 < HD / 4; d4++) {
            float4 kvv = k4[d4], qvv = q4[d4];
            s += qvv.x * kvv.x + qvv.y * kvv.y + qvv.z * kvv.z + qvv.w * kvv.w;
        }
        s *= 0.08838834764831845f;   // 1/sqrt(128)
        sc[kk] = s;
        lmax = fmaxf(lmax, s);
    }
    for (int o2 = 32; o2; o2 >>= 1) lmax = fmaxf(lmax, __shfl_down(lmax, o2, 64));
    if ((tid & 63) == 0) redm[tid >> 6] = lmax;
    __syncthreads();
    float M_ = fmaxf(fmaxf(redm[0], redm[1]), fmaxf(redm[2], redm[3]));
    float lsum = 0.f;
    for (int kk = tid; kk < kn; kk += 256) {
        float e2 = expf(sc[kk] - M_);
        sc[kk] = e2;
        lsum += e2;
    }
    for (int o2 = 32; o2; o2 >>= 1) lsum += __shfl_down(lsum, o2, 64);
    if ((tid & 63) == 0) redz[tid >> 6] = lsum;
    __syncthreads();
    float Z = redz[0] + redz[1] + redz[2] + redz[3];
    int d2 = tid & (HD - 1);
    int halfsel = tid >> 7;
    float acc = 0.f;
    for (int kk = halfsel; kk < kn; kk += 2)
        acc += sc[kk] * v[(size_t)kk * D + hh * HD + d2];
    part[tid] = acc;
    __syncthreads();
    if (tid < HD) o[(size_t)qi * D + hh * HD + tid] = (part[tid] + part[tid + HD]) / Z;
}

// ---------------------------------------------------------------- gate logits: one block per token (skinny N=64)
__global__ __launch_bounds__(256) void gate_kernel(const float* __restrict__ tbuf,
                                                   const float* __restrict__ gate_w,
                                                   float* __restrict__ logits) {
    int tok = blockIdx.x;
    int e    = threadIdx.x >> 2;   // 0..63
    int part = threadIdx.x & 3;    // 0..3
    const float* trow = tbuf   + (size_t)tok * D;
    const float* wrow = gate_w + (size_t)e * D;
    float s = 0.f;
    for (int k = part * 4; k < D; k += 16) {
        float4 a = *(const float4*)(trow + k);
        float4 b = *(const float4*)(wrow + k);
        s += a.x * b.x + a.y * b.y + a.z * b.z + a.w * b.w;
    }
    s += __shfl_down(s, 1, 4);
    s += __shfl_down(s, 2, 4);
    if (part == 0) logits[(size_t)tok * E + e] = s;
}

// ---------------------------------------------------------------- routing (sigmoid gate + group top-k + expert top-k)
__global__ __launch_bounds__(64) void routing_kernel(const float* __restrict__ logits,
                                                     float* __restrict__ gw,
                                                     int* __restrict__ counts,
                                                     int* __restrict__ elist) {
    int t = blockIdx.x;
    int lane = threadIdx.x;
    __shared__ float ss[E];
    if (lane < E) ss[lane] = 1.f / (1.f + expf(-logits[(size_t)t * E + lane]));
    __syncthreads();
    if (lane == 0) {
        float gs[G];
        for (int g = 0; g < G; g++) {
            float m = ss[g * 8];
            for (int j = 1; j < 8; j++) m = fmaxf(m, ss[g * 8 + j]);
            gs[g] = m;
        }
        bool keep[G];
        for (int g = 0; g < G; g++) keep[g] = false;
        for (int r = 0; r < TKG; r++) {
            int best = -1; float bv = -1e30f;
            for (int g = 0; g < G; g++)
                if (!keep[g] && gs[g] > bv) { bv = gs[g]; best = g; }
            keep[best] = true;
        }
        float masked[E];
        for (int e2 = 0; e2 < E; e2++) masked[e2] = keep[e2 >> 3] ? ss[e2] : -1e30f;
        int chosen[TK]; float w[TK]; float wsum = 0.f;
        for (int r = 0; r < TK; r++) {
            int best = 0; float bv = -1e31f;
            for (int e2 = 0; e2 < E; e2++)
                if (masked[e2] > bv) { bv = masked[e2]; best = e2; }
            chosen[r] = best; w[r] = ss[best]; masked[best] = -1e31f; wsum += w[r];
        }
        float scale_ = ROUTE_SCALE / wsum;
        for (int r = 0; r < TK; r++) {
            int slot = t * TK + r;
            gw[slot] = w[r] * scale_;
            int e2 = chosen[r];
            int pos = atomicAdd(&counts[e2], 1);
            elist[e2 * T + pos] = slot;
        }
    }
}

// ---------------------------------------------------------------- MoE up (MFMA): a[slot,i] = silu(t@w1^T) * (t@w3^T)
__global__ __launch_bounds__(256) void moe_up_kernel(const float* __restrict__ tbuf,
                                                     const float* __restrict__ w1,
                                                     const float* __restrict__ w3,
                                                     const int* __restrict__ counts,
                                                     const int* __restrict__ elist,
                                                     float* __restrict__ abuf) {
    const int e = blockIdx.x;
    const int nt = counts[e];
    if (nt == 0) return;
    const int i0 = blockIdx.y * 64;
    const float* W1 = w1 + (size_t)e * I_ * D;
    const float* W3 = w3 + (size_t)e * I_ * D;
    __shared__ unsigned short Ah[64][40], Al[64][40];
    __shared__ unsigned short B1h[64][40], B1l[64][40];
    __shared__ unsigned short B3h[64][40], B3l[64][40];
    __shared__ int slots[64];
    __shared__ const float* rows[64];
    const int tid = threadIdx.x;
    const int w = tid >> 6, lane = tid & 63;
    const int srow = tid >> 2;
    const int skq  = (tid & 3) * 8;
    const int wm = (w >> 1) * 32, wn = (w & 1) * 32;
    const int fr = lane >> 4, fc = lane & 15;
    const float* B1row = W1 + (size_t)(i0 + srow) * D + skq;
    const float* B3row = W3 + (size_t)(i0 + srow) * D + skq;
    const float4 z4 = make_float4(0.f, 0.f, 0.f, 0.f);
    const int KT = D >> 5;   // 64

    for (int tb = 0; tb < nt; tb += 64) {
        if (tid < 64) {
            int sl = (tb + tid < nt) ? elist[e * T + tb + tid] : -1;
            slots[tid] = sl;
            rows[tid] = (sl >= 0) ? (tbuf + (size_t)(sl / TK) * D) : nullptr;
        }
        __syncthreads();
        const float* Ap = rows[srow];
        f32x4 c1[2][2] = {}, c3[2][2] = {};
        float4 pa0, pa1, p10, p11, p30, p31;
        pa0 = Ap ? *(const float4*)(Ap + skq)     : z4;
        pa1 = Ap ? *(const float4*)(Ap + skq + 4) : z4;
        p10 = *(const float4*)(B1row);
        p11 = *(const float4*)(B1row + 4);
        p30 = *(const float4*)(B3row);
        p31 = *(const float4*)(B3row + 4);

        for (int kt = 0; kt < KT; ++kt) {
            __syncthreads();
            {
                ushort8 h, l;
                split8(pa0, pa1, h, l);
                *(ushort8*)&Ah[srow][skq] = h; *(ushort8*)&Al[srow][skq] = l;
                split8(p10, p11, h, l);
                *(ushort8*)&B1h[srow][skq] = h; *(ushort8*)&B1l[srow][skq] = l;
                split8(p30, p31, h, l);
                *(ushort8*)&B3h[srow][skq] = h; *(ushort8*)&B3l[srow][skq] = l;
            }
            __syncthreads();
            if (kt + 1 < KT) {
                const int ko = (kt + 1) * 32 + skq;
                pa0 = Ap ? *(const float4*)(Ap + ko)     : z4;
                pa1 = Ap ? *(const float4*)(Ap + ko + 4) : z4;
                p10 = *(const float4*)(B1row + (kt + 1) * 32);
                p11 = *(const float4*)(B1row + (kt + 1) * 32 + 4);
                p30 = *(const float4*)(B3row + (kt + 1) * 32);
                p31 = *(const float4*)(B3row + (kt + 1) * 32 + 4);
            }
            s16x8 fah[2], fal[2], f1h[2], f1l[2], f3h[2], f3l[2];
#pragma unroll
            for (int mf = 0; mf < 2; ++mf) {
                int r = wm + mf * 16 + fc;
                fah[mf] = ldsfrag(&Ah[r][fr * 8]);
                fal[mf] = ldsfrag(&Al[r][fr * 8]);
            }
#pragma unroll
            for (int nf = 0; nf < 2; ++nf) {
                int r = wn + nf * 16 + fc;
                f1h[nf] = ldsfrag(&B1h[r][fr * 8]);
                f1l[nf] = ldsfrag(&B1l[r][fr * 8]);
                f3h[nf] = ldsfrag(&B3h[r][fr * 8]);
                f3l[nf] = ldsfrag(&B3l[r][fr * 8]);
            }
#pragma unroll
            for (int mf = 0; mf < 2; ++mf)
#pragma unroll
                for (int nf = 0; nf < 2; ++nf) {
                    c1[mf][nf] = __builtin_amdgcn_mfma_f32_16x16x32_bf16(fah[mf], f1h[nf], c1[mf][nf], 0, 0, 0);
                    c1[mf][nf] = __builtin_amdgcn_mfma_f32_16x16x32_bf16(fah[mf], f1l[nf], c1[mf][nf], 0, 0, 0);
                    c1[mf][nf] = __builtin_amdgcn_mfma_f32_16x16x32_bf16(fal[mf], f1h[nf], c1[mf][nf], 0, 0, 0);
                    c3[mf][nf] = __builtin_amdgcn_mfma_f32_16x16x32_bf16(fah[mf], f3h[nf], c3[mf][nf], 0, 0, 0);
                    c3[mf][nf] = __builtin_amdgcn_mfma_f32_16x16x32_bf16(fah[mf], f3l[nf], c3[mf][nf], 0, 0, 0);
                    c3[mf][nf] = __builtin_amdgcn_mfma_f32_16x16x32_bf16(fal[mf], f3h[nf], c3[mf][nf], 0, 0, 0);
                }
        }

#pragma unroll
        for (int mf = 0; mf < 2; ++mf)
#pragma unroll
            for (int nf = 0; nf < 2; ++nf)
#pragma unroll
                for (int r = 0; r < 4; ++r) {
                    int mrow = wm + mf * 16 + fr * 4 + r;
                    if (tb + mrow < nt) {
                        int sl = slots[mrow];
                        float h1 = c1[mf][nf][r];
                        float h3 = c3[mf][nf][r];
                        float o = (h1 / (1.f + expf(-h1))) * h3;
                        abuf[(size_t)sl * I_ + i0 + wn + nf * 16 + fc] = o;
                    }
                }
        __syncthreads();
    }
}

// ---------------------------------------------------------------- MoE down (MFMA): routed[t,:] += gw * a[slot,:] @ w2[e]^T
__global__ __launch_bounds__(256) void moe_down_kernel(const float* __restrict__ abuf,
                                                       const float* __restrict__ w2,
                                                       const int* __restrict__ counts,
                                                       const int* __restrict__ elist,
                                                       const float* __restrict__ gw,
                                                       float* __restrict__ routed) {
    const int e = blockIdx.x;
    const int nt = counts[e];
    if (nt == 0) return;
    const int d0 = blockIdx.y * 64;
    const float* W2 = w2 + (size_t)e * D * I_;   // [d][i]
    __shared__ unsigned short Ah[64][40], Al[64][40], Bh[64][40], Bl[64][40];
    __shared__ int slots[64];
    __shared__ const float* rows[64];
    const int tid = threadIdx.x;
    const int w = tid >> 6, lane = tid & 63;
    const int srow = tid >> 2;
    const int skq  = (tid & 3) * 8;
    const int wm = (w >> 1) * 32, wn = (w & 1) * 32;
    const int fr = lane >> 4, fc = lane & 15;
    const float* Brow = W2 + (size_t)(d0 + srow) * I_ + skq;
    const float4 z4 = make_float4(0.f, 0.f, 0.f, 0.f);
    const int KT = I_ >> 5;   // 16

    for (int tb = 0; tb < nt; tb += 64) {
        if (tid < 64) {
            int sl = (tb + tid < nt) ? elist[e * T + tb + tid] : -1;
            slots[tid] = sl;
            rows[tid] = (sl >= 0) ? (abuf + (size_t)sl * I_) : nullptr;
        }
        __syncthreads();
        const float* Ap = rows[srow];
        f32x4 acc[2][2] = {};
        float4 pa0, pa1, pb0, pb1;
        pa0 = Ap ? *(const float4*)(Ap + skq)     : z4;
        pa1 = Ap ? *(const float4*)(Ap + skq + 4) : z4;
        pb0 = *(const float4*)(Brow);
        pb1 = *(const float4*)(Brow + 4);

        for (int kt = 0; kt < KT; ++kt) {
            __syncthreads();
            {
                ushort8 h, l;
                split8(pa0, pa1, h, l);
                *(ushort8*)&Ah[srow][skq] = h; *(ushort8*)&Al[srow][skq] = l;
                split8(pb0, pb1, h, l);
                *(ushort8*)&Bh[srow][skq] = h; *(ushort8*)&Bl[srow][skq] = l;
            }
            __syncthreads();
            if (kt + 1 < KT) {
                const int ko = (kt + 1) * 32 + skq;
                pa0 = Ap ? *(const float4*)(Ap + ko)     : z4;
                pa1 = Ap ? *(const float4*)(Ap + ko + 4) : z4;
                pb0 = *(const float4*)(Brow + (kt + 1) * 32);
                pb1 = *(const float4*)(Brow + (kt + 1) * 32 + 4);
            }
            s16x8 fah[2], fal[2], fbh[2], fbl[2];
#pragma unroll
            for (int mf = 0; mf < 2; ++mf) {
                int r = wm + mf * 16 + fc;
                fah[mf] = ldsfrag(&Ah[r][fr * 8]);
                fal[mf] = ldsfrag(&Al[r][fr * 8]);
            }
#pragma unroll
            for (int nf = 0; nf < 2; ++nf) {
                int r = wn + nf * 16 + fc;
                fbh[nf] = ldsfrag(&Bh[r][fr * 8]);
                fbl[nf] = ldsfrag(&Bl[r][fr * 8]);
            }
#pragma unroll
            for (int mf = 0; mf < 2; ++mf)
#pragma unroll
                for (int nf = 0; nf < 2; ++nf) {
                    acc[mf][nf] = __builtin_amdgcn_mfma_f32_16x16x32_bf16(fah[mf], fbh[nf], acc[mf][nf], 0, 0, 0);
                    acc[mf][nf] = __builtin_amdgcn_mfma_f32_16x16x32_bf16(fah[mf], fbl[nf], acc[mf][nf], 0, 0, 0);
                    acc[mf][nf] = __builtin_amdgcn_mfma_f32_16x16x32_bf16(fal[mf], fbh[nf], acc[mf][nf], 0, 0, 0);
                }
        }

#pragma unroll
        for (int mf = 0; mf < 2; ++mf)
#pragma unroll
            for (int nf = 0; nf < 2; ++nf)
#pragma unroll
                for (int r = 0; r < 4; ++r) {
                    int mrow = wm + mf * 16 + fr * 4 + r;
                    if (tb + mrow < nt) {
                        int sl = slots[mrow];
                        float g = gw[sl];
                        int t = sl / TK;
                        atomicAdd(&routed[(size_t)t * D + d0 + wn + nf * 16 + fc], g * acc[mf][nf][r]);
                    }
                }
        __syncthreads();
    }
}

// ---------------------------------------------------------------- elementwise
__global__ __launch_bounds__(256) void silu_mul_kernel(const float* __restrict__ a,
                                                       const float* __restrict__ b,
                                                       float* __restrict__ o, int n) {
    int i = blockIdx.x * 256 + threadIdx.x;
    if (i < n) { float x = a[i]; o[i] = x / (1.f + expf(-x)) * b[i]; }
}

__global__ __launch_bounds__(256) void add_inplace_kernel(float* __restrict__ o,
                                                          const float* __restrict__ a, int n) {
    int i = blockIdx.x * 256 + threadIdx.x;
    if (i < n) o[i] += a[i];
}

// ---------------------------------------------------------------- launch
extern "C" void kernel_launch(void* const* d_in, const int* in_sizes, int n_in,
                              void* d_out, int out_size, void* d_ws, size_t ws_size,
                              hipStream_t stream) {
    (void)in_sizes; (void)n_in; (void)out_size; (void)ws_size;
    const float* x      = (const float*)d_in[0];
    const float* fc     = (const float*)d_in[1];
    const float* fs     = (const float*)d_in[2];
    // d_in[3] mask: causality handled analytically
    const float* anw    = (const float*)d_in[4];
    const float* fnw    = (const float*)d_in[5];
    const float* wq     = (const float*)d_in[6];
    const float* wk     = (const float*)d_in[7];
    const float* wv     = (const float*)d_in[8];
    const float* wo     = (const float*)d_in[9];
    const float* gate_w = (const float*)d_in[10];
    const float* ew1    = (const float*)d_in[11];
    const float* ew2    = (const float*)d_in[12];
    const float* ew3    = (const float*)d_in[13];
    const float* sw1    = (const float*)d_in[14];
    const float* sw2    = (const float*)d_in[15];
    const float* sw3    = (const float*)d_in[16];
    float* out = (float*)d_out;

    char* wsp = (char*)d_ws;
    size_t off = 0;
    auto alloc = [&](size_t bytes) {
        void* p = wsp + off;
        off += (bytes + 255) & ~(size_t)255;
        return p;
    };
    float* hbuf   = (float*)alloc((size_t)T * D * 4);
    float* qbuf   = (float*)alloc((size_t)T * D * 4);
    float* kbuf   = (float*)alloc((size_t)T * D * 4);
    float* vbuf   = (float*)alloc((size_t)T * D * 4);
    float* attnb  = (float*)alloc((size_t)T * D * 4);
    float* x1     = (float*)alloc((size_t)T * D * 4);
    float* tbuf   = (float*)alloc((size_t)T * D * 4);
    float* routed = (float*)alloc((size_t)T * D * 4);
    float* logits = (float*)alloc((size_t)T * E * 4);
    float* gwbuf  = (float*)alloc((size_t)T * TK * 4);
    int*   counts = (int*)alloc(E * 4);
    int*   elist  = (int*)alloc((size_t)E * T * 4);
    float* abuf   = (float*)alloc((size_t)T * TK * I_ * 4);
    float* u1     = (float*)alloc((size_t)T * SH_I * 4);
    float* u3     = (float*)alloc((size_t)T * SH_I * 4);
    float* ub     = (float*)alloc((size_t)T * SH_I * 4);

    hipMemsetAsync(counts, 0, E * 4, stream);
    hipMemsetAsync(routed, 0, (size_t)T * D * 4, stream);

    // attention branch
    rmsnorm_kernel<<<T, 256, 0, stream>>>(x, anw, hbuf);
    // fused QKV: z selects weight/output
    mgemm_nt_kernel<<<dim3(D / 64, T / 64, 3), 256, 0, stream>>>(hbuf, wq, wk, wv,
                                                                 qbuf, kbuf, vbuf,
                                                                 nullptr, T, D, D);
    rope_kernel<<<(T * H * HD / 2) / 256, 256, 0, stream>>>(qbuf, kbuf, fc, fs);
    attn_kernel<<<dim3(S, H), 256, 0, stream>>>(qbuf, kbuf, vbuf, attnb);
    mgemm_nt_kernel<<<dim3(D / 64, T / 64, 1), 256, 0, stream>>>(attnb, wo, wo, wo,
                                                                 x1, x1, x1,
                                                                 x, T, D, D);

    // FFN branch
    rmsnorm_kernel<<<T, 256, 0, stream>>>(x1, fnw, tbuf);
    gate_kernel<<<T, 256, 0, stream>>>(tbuf, gate_w, logits);
    routing_kernel<<<T, 64, 0, stream>>>(logits, gwbuf, counts, elist);
    moe_up_kernel<<<dim3(E, I_ / 64), 256, 0, stream>>>(tbuf, ew1, ew3, counts, elist, abuf);
    moe_down_kernel<<<dim3(E, D / 64), 256, 0, stream>>>(abuf, ew2, counts, elist, gwbuf, routed);

    // shared expert: sw1/sw3 fused via z
    mgemm_nt_kernel<<<dim3(SH_I / 64, T / 64, 2), 256, 0, stream>>>(tbuf, sw1, sw3, sw3,
                                                                    u1, u3, u3,
                                                                    nullptr, T, SH_I, D);
    silu_mul_kernel<<<(T * SH_I) / 256, 256, 0, stream>>>(u1, u3, ub, T * SH_I);
    mgemm_nt_kernel<<<dim3(D / 64, T / 64, 1), 256, 0, stream>>>(ub, sw2, sw2, sw2,
                                                                 out, out, out,
                                                                 x1, T, D, SH_I);
    add_inplace_kernel<<<(T * D) / 256, 256, 0, stream>>>(out, routed, T * D);
}

// Round 4
// 1397.896 us; speedup vs baseline: 2.2619x; 1.2001x over previous
//
#include <hip/hip_runtime.h>
#include <hip/hip_bf16.h>
#include <math.h>

// Problem constants (from reference)
constexpr int S   = 512;
constexpr int D   = 2048;
constexpr int H   = 16;
constexpr int HD  = 128;
constexpr int T   = 512;     // B*S
constexpr int E   = 64;
constexpr int I_  = 512;
constexpr int G   = 8;
constexpr int TKG = 4;
constexpr int TK  = 6;
constexpr int SH_I = 1024;
constexpr float ROUTE_SCALE = 2.5f;
constexpr float EPS = 1e-5f;

typedef short   s16x8   __attribute__((ext_vector_type(8)));
typedef unsigned short ushort8 __attribute__((ext_vector_type(8)));
typedef float   f32x4   __attribute__((ext_vector_type(4)));

// split fp32 -> (hi, lo) bf16 bit patterns; hi RNE, lo = bf16(x - hi)
__device__ inline void split8(const float4& x0, const float4& x1, ushort8& h, ushort8& l) {
    float xs[8] = {x0.x, x0.y, x0.z, x0.w, x1.x, x1.y, x1.z, x1.w};
#pragma unroll
    for (int j = 0; j < 8; ++j) {
        __bf16 hb = (__bf16)xs[j];
        float hf = (float)hb;
        __bf16 lb = (__bf16)(xs[j] - hf);
        h[j] = __builtin_bit_cast(unsigned short, hb);
        l[j] = __builtin_bit_cast(unsigned short, lb);
    }
}

__device__ inline s16x8 ldsfrag(const unsigned short* p) {
    return *(const s16x8*)p;
}

__device__ inline s16x8 as_s16(ushort8 u) {
    return __builtin_bit_cast(s16x8, u);
}

// ---------------------------------------------------------------- rmsnorm
__global__ __launch_bounds__(256) void rmsnorm_kernel(const float* __restrict__ x,
                                                      const float* __restrict__ w,
                                                      float* __restrict__ out) {
    int t = blockIdx.x;
    int tid = threadIdx.x;
    const float* row = x + (size_t)t * D;
    float ss = 0.f;
    for (int i = tid; i < D; i += 256) { float v = row[i]; ss += v * v; }
    for (int o = 32; o; o >>= 1) ss += __shfl_down(ss, o, 64);
    __shared__ float red[4];
    if ((tid & 63) == 0) red[tid >> 6] = ss;
    __syncthreads();
    float tot = red[0] + red[1] + red[2] + red[3];
    float scale = rsqrtf(tot / (float)D + EPS);
    for (int i = tid; i < D; i += 256) out[(size_t)t * D + i] = row[i] * scale * w[i];
}

// ---------------------------------------------------------------- MFMA GEMM: C = A(MxK) @ B(NxK)^T (+ addsrc)
__global__ __launch_bounds__(256) void mgemm_nt_kernel(const float* __restrict__ A,
                                                       const float* __restrict__ B0,
                                                       const float* __restrict__ B1,
                                                       const float* __restrict__ B2,
                                                       float* __restrict__ C0,
                                                       float* __restrict__ C1,
                                                       float* __restrict__ C2,
                                                       const float* __restrict__ addsrc,
                                                       int M, int N, int K) {
    (void)M;
    const float* B = (blockIdx.z == 0) ? B0 : ((blockIdx.z == 1) ? B1 : B2);
    float*       C = (blockIdx.z == 0) ? C0 : ((blockIdx.z == 1) ? C1 : C2);
    __shared__ unsigned short Ah[64][40], Al[64][40], Bh[64][40], Bl[64][40];
    const int m0 = blockIdx.y * 64, n0 = blockIdx.x * 64;
    const int tid = threadIdx.x;
    const int w = tid >> 6, lane = tid & 63;
    const int srow = tid >> 2;          // staging row 0..63
    const int skq  = (tid & 3) * 8;     // staging k offset 0,8,16,24
    const int wm = (w >> 1) * 32, wn = (w & 1) * 32;
    const int fr = lane >> 4, fc = lane & 15;
    const float* Arow = A + (size_t)(m0 + srow) * K + skq;
    const float* Brow = B + (size_t)(n0 + srow) * K + skq;

    f32x4 acc[2][2] = {};
    const int KT = K >> 5;
    float4 pa0 = *(const float4*)(Arow);
    float4 pa1 = *(const float4*)(Arow + 4);
    float4 pb0 = *(const float4*)(Brow);
    float4 pb1 = *(const float4*)(Brow + 4);

    for (int kt = 0; kt < KT; ++kt) {
        __syncthreads();
        {
            ushort8 h, l;
            split8(pa0, pa1, h, l);
            *(ushort8*)&Ah[srow][skq] = h; *(ushort8*)&Al[srow][skq] = l;
            split8(pb0, pb1, h, l);
            *(ushort8*)&Bh[srow][skq] = h; *(ushort8*)&Bl[srow][skq] = l;
        }
        __syncthreads();
        if (kt + 1 < KT) {
            const float* An = Arow + (kt + 1) * 32;
            const float* Bn = Brow + (kt + 1) * 32;
            pa0 = *(const float4*)(An); pa1 = *(const float4*)(An + 4);
            pb0 = *(const float4*)(Bn); pb1 = *(const float4*)(Bn + 4);
        }
        s16x8 fah[2], fal[2], fbh[2], fbl[2];
#pragma unroll
        for (int mf = 0; mf < 2; ++mf) {
            int r = wm + mf * 16 + fc;
            fah[mf] = ldsfrag(&Ah[r][fr * 8]);
            fal[mf] = ldsfrag(&Al[r][fr * 8]);
        }
#pragma unroll
        for (int nf = 0; nf < 2; ++nf) {
            int r = wn + nf * 16 + fc;
            fbh[nf] = ldsfrag(&Bh[r][fr * 8]);
            fbl[nf] = ldsfrag(&Bl[r][fr * 8]);
        }
#pragma unroll
        for (int mf = 0; mf < 2; ++mf)
#pragma unroll
            for (int nf = 0; nf < 2; ++nf) {
                acc[mf][nf] = __builtin_amdgcn_mfma_f32_16x16x32_bf16(fah[mf], fbh[nf], acc[mf][nf], 0, 0, 0);
                acc[mf][nf] = __builtin_amdgcn_mfma_f32_16x16x32_bf16(fah[mf], fbl[nf], acc[mf][nf], 0, 0, 0);
                acc[mf][nf] = __builtin_amdgcn_mfma_f32_16x16x32_bf16(fal[mf], fbh[nf], acc[mf][nf], 0, 0, 0);
            }
    }

#pragma unroll
    for (int mf = 0; mf < 2; ++mf)
#pragma unroll
        for (int nf = 0; nf < 2; ++nf)
#pragma unroll
            for (int r = 0; r < 4; ++r) {
                int gm = m0 + wm + mf * 16 + fr * 4 + r;
                int gn = n0 + wn + nf * 16 + fc;
                size_t off = (size_t)gm * N + gn;
                float v = acc[mf][nf][r];
                if (addsrc) v += addsrc[off];
                C[off] = v;
            }
}

// ---------------------------------------------------------------- RoPE (in-place on q and k)
__global__ __launch_bounds__(256) void rope_kernel(float* __restrict__ q, float* __restrict__ k,
                                                   const float* __restrict__ fc,
                                                   const float* __restrict__ fs) {
    int idx = blockIdx.x * 256 + threadIdx.x;   // T*H*(HD/2)
    int p  = idx & (HD / 2 - 1);
    int hh = (idx >> 6) & (H - 1);
    int t  = idx >> 10;
    float c = fc[t * (HD / 2) + p], s = fs[t * (HD / 2) + p];
    size_t base = (size_t)t * D + hh * HD + p * 2;
    float re = q[base], im = q[base + 1];
    q[base]     = re * c - im * s;
    q[base + 1] = re * s + im * c;
    re = k[base]; im = k[base + 1];
    k[base]     = re * c - im * s;
    k[base + 1] = re * s + im * c;
}

// ---------------------------------------------------------------- flash attention (MFMA, split-bf16)
// grid (S/64, H), 256 threads = 4 waves; wave w owns q rows [q0+w*16, +16).
// Per 32-key tile: stage K (split, gemm layout) + V^T (split), QK^T via MFMA,
// online softmax (shfl butterfly), P->bf16 hi/lo via LDS relayout, PV via MFMA.
__global__ __launch_bounds__(256) void attn_mfma_kernel(const float* __restrict__ q,
                                                        const float* __restrict__ k,
                                                        const float* __restrict__ v,
                                                        float* __restrict__ o) {
    const int qt = blockIdx.x, h = blockIdx.y;
    const int q0 = qt * 64;
    const int tid = threadIdx.x;
    const int w = tid >> 6, lane = tid & 63;
    const int fc = lane & 15, fr = lane >> 4;
    __shared__ unsigned short Kh[4][32][40], Kl[4][32][40];     // [kchunk][key][kdim]
    __shared__ unsigned short Vth[128][44], Vtl[128][44];       // [d][key]
    __shared__ unsigned short Pbh[4][16][38], Pbl[4][16][38];   // [wave][q][key]

    // Q fragments in registers (A-operand: row = lane&15, k = fr*8+j + 32*ks)
    ushort8 qh[4], ql[4];
    {
        const float* qrow = q + (size_t)(q0 + w * 16 + fc) * D + h * HD;
#pragma unroll
        for (int ks = 0; ks < 4; ++ks) {
            float4 a = *(const float4*)(qrow + ks * 32 + fr * 8);
            float4 b = *(const float4*)(qrow + ks * 32 + fr * 8 + 4);
            split8(a, b, qh[ks], ql[ks]);
        }
    }

    f32x4 accO[8] = {};
    float mold[4] = {-3e38f, -3e38f, -3e38f, -3e38f};
    float lsum[4] = {};
    const int NT = 2 * qt + 2;

    for (int kt = 0; kt < NT; ++kt) {
        const int k0 = kt * 32;
        __syncthreads();   // previous tile fully consumed
#pragma unroll
        for (int rep = 0; rep < 2; ++rep) {
            int e = rep * 256 + tid;
            int key = e >> 4;          // 0..31
            int dq  = (e & 15) * 8;    // 0..120
            const float* kr = k + (size_t)(k0 + key) * D + h * HD + dq;
            const float* vr = v + (size_t)(k0 + key) * D + h * HD + dq;
            float4 a = *(const float4*)kr, b = *(const float4*)(kr + 4);
            ushort8 hh, ll;
            split8(a, b, hh, ll);
            *(ushort8*)&Kh[dq >> 5][key][dq & 31] = hh;
            *(ushort8*)&Kl[dq >> 5][key][dq & 31] = ll;
            a = *(const float4*)vr; b = *(const float4*)(vr + 4);
            split8(a, b, hh, ll);
#pragma unroll
            for (int j = 0; j < 8; ++j) { Vth[dq + j][key] = hh[j]; Vtl[dq + j][key] = ll[j]; }
        }
        __syncthreads();

        // QK^T: C[q][key], 2 key-frags x 4 k-steps x 3 split products
        f32x4 sc[2] = {};
#pragma unroll
        for (int kf = 0; kf < 2; ++kf) {
#pragma unroll
            for (int ks = 0; ks < 4; ++ks) {
                s16x8 kbh = ldsfrag(&Kh[ks][kf * 16 + fc][fr * 8]);
                s16x8 kbl = ldsfrag(&Kl[ks][kf * 16 + fc][fr * 8]);
                sc[kf] = __builtin_amdgcn_mfma_f32_16x16x32_bf16(as_s16(qh[ks]), kbh, sc[kf], 0, 0, 0);
                sc[kf] = __builtin_amdgcn_mfma_f32_16x16x32_bf16(as_s16(qh[ks]), kbl, sc[kf], 0, 0, 0);
                sc[kf] = __builtin_amdgcn_mfma_f32_16x16x32_bf16(as_s16(ql[ks]), kbh, sc[kf], 0, 0, 0);
            }
        }

        const bool diag = (k0 + 31 > q0);   // tile may cross the causal diagonal
        float p2[2][4], fscv[4];
#pragma unroll
        for (int r = 0; r < 4; ++r) {
            const int qrow = q0 + w * 16 + fr * 4 + r;
#pragma unroll
            for (int kf = 0; kf < 2; ++kf) {
                float sv = sc[kf][r] * 0.08838834764831845f;
                if (diag && (k0 + kf * 16 + fc) > qrow) sv = -3e38f;
                sc[kf][r] = sv;
            }
            float mx = fmaxf(sc[0][r], sc[1][r]);
            mx = fmaxf(mx, __shfl_xor(mx, 1, 64));
            mx = fmaxf(mx, __shfl_xor(mx, 2, 64));
            mx = fmaxf(mx, __shfl_xor(mx, 4, 64));
            mx = fmaxf(mx, __shfl_xor(mx, 8, 64));
            float mn = fmaxf(mold[r], mx);
            float fs = expf(mold[r] - mn);
            float s0 = expf(sc[0][r] - mn);
            float s1 = expf(sc[1][r] - mn);
            p2[0][r] = s0; p2[1][r] = s1;
            float rs = s0 + s1;
            rs += __shfl_xor(rs, 1, 64);
            rs += __shfl_xor(rs, 2, 64);
            rs += __shfl_xor(rs, 4, 64);
            rs += __shfl_xor(rs, 8, 64);
            lsum[r] = lsum[r] * fs + rs;
            mold[r] = mn; fscv[r] = fs;
        }
#pragma unroll
        for (int df = 0; df < 8; ++df)
#pragma unroll
            for (int r = 0; r < 4; ++r) accO[df][r] *= fscv[r];

        // P -> bf16 hi/lo, relayout via per-wave LDS buffer
#pragma unroll
        for (int kf = 0; kf < 2; ++kf)
#pragma unroll
            for (int r = 0; r < 4; ++r) {
                __bf16 hb = (__bf16)p2[kf][r];
                float hf = (float)hb;
                __bf16 lb = (__bf16)(p2[kf][r] - hf);
                Pbh[w][fr * 4 + r][kf * 16 + fc] = __builtin_bit_cast(unsigned short, hb);
                Pbl[w][fr * 4 + r][kf * 16 + fc] = __builtin_bit_cast(unsigned short, lb);
            }
        s16x8 pah = ldsfrag(&Pbh[w][fc][fr * 8]);
        s16x8 pal = ldsfrag(&Pbl[w][fc][fr * 8]);
#pragma unroll
        for (int df = 0; df < 8; ++df) {
            s16x8 vbh = ldsfrag(&Vth[df * 16 + fc][fr * 8]);
            s16x8 vbl = ldsfrag(&Vtl[df * 16 + fc][fr * 8]);
            accO[df] = __builtin_amdgcn_mfma_f32_16x16x32_bf16(pah, vbh, accO[df], 0, 0, 0);
            accO[df] = __builtin_amdgcn_mfma_f32_16x16x32_bf16(pah, vbl, accO[df], 0, 0, 0);
            accO[df] = __builtin_amdgcn_mfma_f32_16x16x32_bf16(pal, vbh, accO[df], 0, 0, 0);
        }
    }

#pragma unroll
    for (int df = 0; df < 8; ++df)
#pragma unroll
        for (int r = 0; r < 4; ++r) {
            int qrow = q0 + w * 16 + fr * 4 + r;
            o[(size_t)qrow * D + h * HD + df * 16 + fc] = accO[df][r] / lsum[r];
        }
}

// ---------------------------------------------------------------- gate logits: one block per token (skinny N=64)
__global__ __launch_bounds__(256) void gate_kernel(const float* __restrict__ tbuf,
                                                   const float* __restrict__ gate_w,
                                                   float* __restrict__ logits) {
    int tok = blockIdx.x;
    int e    = threadIdx.x >> 2;   // 0..63
    int part = threadIdx.x & 3;    // 0..3
    const float* trow = tbuf   + (size_t)tok * D;
    const float* wrow = gate_w + (size_t)e * D;
    float s = 0.f;
    for (int k = part * 4; k < D; k += 16) {
        float4 a = *(const float4*)(trow + k);
        float4 b = *(const float4*)(wrow + k);
        s += a.x * b.x + a.y * b.y + a.z * b.z + a.w * b.w;
    }
    s += __shfl_down(s, 1, 4);
    s += __shfl_down(s, 2, 4);
    if (part == 0) logits[(size_t)tok * E + e] = s;
}

// ---------------------------------------------------------------- routing (sigmoid gate + group top-k + expert top-k)
__global__ __launch_bounds__(64) void routing_kernel(const float* __restrict__ logits,
                                                     float* __restrict__ gw,
                                                     int* __restrict__ counts,
                                                     int* __restrict__ elist) {
    int t = blockIdx.x;
    int lane = threadIdx.x;
    __shared__ float ss[E];
    if (lane < E) ss[lane] = 1.f / (1.f + expf(-logits[(size_t)t * E + lane]));
    __syncthreads();
    if (lane == 0) {
        float gs[G];
        for (int g = 0; g < G; g++) {
            float m = ss[g * 8];
            for (int j = 1; j < 8; j++) m = fmaxf(m, ss[g * 8 + j]);
            gs[g] = m;
        }
        bool keep[G];
        for (int g = 0; g < G; g++) keep[g] = false;
        for (int r = 0; r < TKG; r++) {
            int best = -1; float bv = -1e30f;
            for (int g = 0; g < G; g++)
                if (!keep[g] && gs[g] > bv) { bv = gs[g]; best = g; }
            keep[best] = true;
        }
        float masked[E];
        for (int e2 = 0; e2 < E; e2++) masked[e2] = keep[e2 >> 3] ? ss[e2] : -1e30f;
        int chosen[TK]; float w[TK]; float wsum = 0.f;
        for (int r = 0; r < TK; r++) {
            int best = 0; float bv = -1e31f;
            for (int e2 = 0; e2 < E; e2++)
                if (masked[e2] > bv) { bv = masked[e2]; best = e2; }
            chosen[r] = best; w[r] = ss[best]; masked[best] = -1e31f; wsum += w[r];
        }
        float scale_ = ROUTE_SCALE / wsum;
        for (int r = 0; r < TK; r++) {
            int slot = t * TK + r;
            gw[slot] = w[r] * scale_;
            int e2 = chosen[r];
            int pos = atomicAdd(&counts[e2], 1);
            elist[e2 * T + pos] = slot;
        }
    }
}

// ---------------------------------------------------------------- MoE up (MFMA): a[slot,i] = silu(t@w1^T) * (t@w3^T)
__global__ __launch_bounds__(256) void moe_up_kernel(const float* __restrict__ tbuf,
                                                     const float* __restrict__ w1,
                                                     const float* __restrict__ w3,
                                                     const int* __restrict__ counts,
                                                     const int* __restrict__ elist,
                                                     float* __restrict__ abuf) {
    const int e = blockIdx.x;
    const int nt = counts[e];
    if (nt == 0) return;
    const int i0 = blockIdx.y * 64;
    const float* W1 = w1 + (size_t)e * I_ * D;
    const float* W3 = w3 + (size_t)e * I_ * D;
    __shared__ unsigned short Ah[64][40], Al[64][40];
    __shared__ unsigned short B1h[64][40], B1l[64][40];
    __shared__ unsigned short B3h[64][40], B3l[64][40];
    __shared__ int slots[64];
    __shared__ const float* rows[64];
    const int tid = threadIdx.x;
    const int w = tid >> 6, lane = tid & 63;
    const int srow = tid >> 2;
    const int skq  = (tid & 3) * 8;
    const int wm = (w >> 1) * 32, wn = (w & 1) * 32;
    const int fr = lane >> 4, fc = lane & 15;
    const float* B1row = W1 + (size_t)(i0 + srow) * D + skq;
    const float* B3row = W3 + (size_t)(i0 + srow) * D + skq;
    const float4 z4 = make_float4(0.f, 0.f, 0.f, 0.f);
    const int KT = D >> 5;   // 64

    for (int tb = 0; tb < nt; tb += 64) {
        if (tid < 64) {
            int sl = (tb + tid < nt) ? elist[e * T + tb + tid] : -1;
            slots[tid] = sl;
            rows[tid] = (sl >= 0) ? (tbuf + (size_t)(sl / TK) * D) : nullptr;
        }
        __syncthreads();
        const float* Ap = rows[srow];
        f32x4 c1[2][2] = {}, c3[2][2] = {};
        float4 pa0, pa1, p10, p11, p30, p31;
        pa0 = Ap ? *(const float4*)(Ap + skq)     : z4;
        pa1 = Ap ? *(const float4*)(Ap + skq + 4) : z4;
        p10 = *(const float4*)(B1row);
        p11 = *(const float4*)(B1row + 4);
        p30 = *(const float4*)(B3row);
        p31 = *(const float4*)(B3row + 4);

        for (int kt = 0; kt < KT; ++kt) {
            __syncthreads();
            {
                ushort8 h, l;
                split8(pa0, pa1, h, l);
                *(ushort8*)&Ah[srow][skq] = h; *(ushort8*)&Al[srow][skq] = l;
                split8(p10, p11, h, l);
                *(ushort8*)&B1h[srow][skq] = h; *(ushort8*)&B1l[srow][skq] = l;
                split8(p30, p31, h, l);
                *(ushort8*)&B3h[srow][skq] = h; *(ushort8*)&B3l[srow][skq] = l;
            }
            __syncthreads();
            if (kt + 1 < KT) {
                const int ko = (kt + 1) * 32 + skq;
                pa0 = Ap ? *(const float4*)(Ap + ko)     : z4;
                pa1 = Ap ? *(const float4*)(Ap + ko + 4) : z4;
                p10 = *(const float4*)(B1row + (kt + 1) * 32);
                p11 = *(const float4*)(B1row + (kt + 1) * 32 + 4);
                p30 = *(const float4*)(B3row + (kt + 1) * 32);
                p31 = *(const float4*)(B3row + (kt + 1) * 32 + 4);
            }
            s16x8 fah[2], fal[2], f1h[2], f1l[2], f3h[2], f3l[2];
#pragma unroll
            for (int mf = 0; mf < 2; ++mf) {
                int r = wm + mf * 16 + fc;
                fah[mf] = ldsfrag(&Ah[r][fr * 8]);
                fal[mf] = ldsfrag(&Al[r][fr * 8]);
            }
#pragma unroll
            for (int nf = 0; nf < 2; ++nf) {
                int r = wn + nf * 16 + fc;
                f1h[nf] = ldsfrag(&B1h[r][fr * 8]);
                f1l[nf] = ldsfrag(&B1l[r][fr * 8]);
                f3h[nf] = ldsfrag(&B3h[r][fr * 8]);
                f3l[nf] = ldsfrag(&B3l[r][fr * 8]);
            }
#pragma unroll
            for (int mf = 0; mf < 2; ++mf)
#pragma unroll
                for (int nf = 0; nf < 2; ++nf) {
                    c1[mf][nf] = __builtin_amdgcn_mfma_f32_16x16x32_bf16(fah[mf], f1h[nf], c1[mf][nf], 0, 0, 0);
                    c1[mf][nf] = __builtin_amdgcn_mfma_f32_16x16x32_bf16(fah[mf], f1l[nf], c1[mf][nf], 0, 0, 0);
                    c1[mf][nf] = __builtin_amdgcn_mfma_f32_16x16x32_bf16(fal[mf], f1h[nf], c1[mf][nf], 0, 0, 0);
                    c3[mf][nf] = __builtin_amdgcn_mfma_f32_16x16x32_bf16(fah[mf], f3h[nf], c3[mf][nf], 0, 0, 0);
                    c3[mf][nf] = __builtin_amdgcn_mfma_f32_16x16x32_bf16(fah[mf], f3l[nf], c3[mf][nf], 0, 0, 0);
                    c3[mf][nf] = __builtin_amdgcn_mfma_f32_16x16x32_bf16(fal[mf], f3h[nf], c3[mf][nf], 0, 0, 0);
                }
        }

#pragma unroll
        for (int mf = 0; mf < 2; ++mf)
#pragma unroll
            for (int nf = 0; nf < 2; ++nf)
#pragma unroll
                for (int r = 0; r < 4; ++r) {
                    int mrow = wm + mf * 16 + fr * 4 + r;
                    if (tb + mrow < nt) {
                        int sl = slots[mrow];
                        float h1 = c1[mf][nf][r];
                        float h3 = c3[mf][nf][r];
                        float o = (h1 / (1.f + expf(-h1))) * h3;
                        abuf[(size_t)sl * I_ + i0 + wn + nf * 16 + fc] = o;
                    }
                }
        __syncthreads();
    }
}

// ---------------------------------------------------------------- MoE down (MFMA): routed[t,:] += gw * a[slot,:] @ w2[e]^T
__global__ __launch_bounds__(256) void moe_down_kernel(const float* __restrict__ abuf,
                                                       const float* __restrict__ w2,
                                                       const int* __restrict__ counts,
                                                       const int* __restrict__ elist,
                                                       const float* __restrict__ gw,
                                                       float* __restrict__ routed) {
    const int e = blockIdx.x;
    const int nt = counts[e];
    if (nt == 0) return;
    const int d0 = blockIdx.y * 64;
    const float* W2 = w2 + (size_t)e * D * I_;   // [d][i]
    __shared__ unsigned short Ah[64][40], Al[64][40], Bh[64][40], Bl[64][40];
    __shared__ int slots[64];
    __shared__ const float* rows[64];
    const int tid = threadIdx.x;
    const int w = tid >> 6, lane = tid & 63;
    const int srow = tid >> 2;
    const int skq  = (tid & 3) * 8;
    const int wm = (w >> 1) * 32, wn = (w & 1) * 32;
    const int fr = lane >> 4, fc = lane & 15;
    const float* Brow = W2 + (size_t)(d0 + srow) * I_ + skq;
    const float4 z4 = make_float4(0.f, 0.f, 0.f, 0.f);
    const int KT = I_ >> 5;   // 16

    for (int tb = 0; tb < nt; tb += 64) {
        if (tid < 64) {
            int sl = (tb + tid < nt) ? elist[e * T + tb + tid] : -1;
            slots[tid] = sl;
            rows[tid] = (sl >= 0) ? (abuf + (size_t)sl * I_) : nullptr;
        }
        __syncthreads();
        const float* Ap = rows[srow];
        f32x4 acc[2][2] = {};
        float4 pa0, pa1, pb0, pb1;
        pa0 = Ap ? *(const float4*)(Ap + skq)     : z4;
        pa1 = Ap ? *(const float4*)(Ap + skq + 4) : z4;
        pb0 = *(const float4*)(Brow);
        pb1 = *(const float4*)(Brow + 4);

        for (int kt = 0; kt < KT; ++kt) {
            __syncthreads();
            {
                ushort8 h, l;
                split8(pa0, pa1, h, l);
                *(ushort8*)&Ah[srow][skq] = h; *(ushort8*)&Al[srow][skq] = l;
                split8(pb0, pb1, h, l);
                *(ushort8*)&Bh[srow][skq] = h; *(ushort8*)&Bl[srow][skq] = l;
            }
            __syncthreads();
            if (kt + 1 < KT) {
                const int ko = (kt + 1) * 32 + skq;
                pa0 = Ap ? *(const float4*)(Ap + ko)     : z4;
                pa1 = Ap ? *(const float4*)(Ap + ko + 4) : z4;
                pb0 = *(const float4*)(Brow + (kt + 1) * 32);
                pb1 = *(const float4*)(Brow + (kt + 1) * 32 + 4);
            }
            s16x8 fah[2], fal[2], fbh[2], fbl[2];
#pragma unroll
            for (int mf = 0; mf < 2; ++mf) {
                int r = wm + mf * 16 + fc;
                fah[mf] = ldsfrag(&Ah[r][fr * 8]);
                fal[mf] = ldsfrag(&Al[r][fr * 8]);
            }
#pragma unroll
            for (int nf = 0; nf < 2; ++nf) {
                int r = wn + nf * 16 + fc;
                fbh[nf] = ldsfrag(&Bh[r][fr * 8]);
                fbl[nf] = ldsfrag(&Bl[r][fr * 8]);
            }
#pragma unroll
            for (int mf = 0; mf < 2; ++mf)
#pragma unroll
                for (int nf = 0; nf < 2; ++nf) {
                    acc[mf][nf] = __builtin_amdgcn_mfma_f32_16x16x32_bf16(fah[mf], fbh[nf], acc[mf][nf], 0, 0, 0);
                    acc[mf][nf] = __builtin_amdgcn_mfma_f32_16x16x32_bf16(fah[mf], fbl[nf], acc[mf][nf], 0, 0, 0);
                    acc[mf][nf] = __builtin_amdgcn_mfma_f32_16x16x32_bf16(fal[mf], fbh[nf], acc[mf][nf], 0, 0, 0);
                }
        }

#pragma unroll
        for (int mf = 0; mf < 2; ++mf)
#pragma unroll
            for (int nf = 0; nf < 2; ++nf)
#pragma unroll
                for (int r = 0; r < 4; ++r) {
                    int mrow = wm + mf * 16 + fr * 4 + r;
                    if (tb + mrow < nt) {
                        int sl = slots[mrow];
                        float g = gw[sl];
                        int t = sl / TK;
                        atomicAdd(&routed[(size_t)t * D + d0 + wn + nf * 16 + fc], g * acc[mf][nf][r]);
                    }
                }
        __syncthreads();
    }
}

// ---------------------------------------------------------------- elementwise
__global__ __launch_bounds__(256) void silu_mul_kernel(const float* __restrict__ a,
                                                       const float* __restrict__ b,
                                                       float* __restrict__ o, int n) {
    int i = blockIdx.x * 256 + threadIdx.x;
    if (i < n) { float x = a[i]; o[i] = x / (1.f + expf(-x)) * b[i]; }
}

__global__ __launch_bounds__(256) void add_inplace_kernel(float* __restrict__ o,
                                                          const float* __restrict__ a, int n) {
    int i = blockIdx.x * 256 + threadIdx.x;
    if (i < n) o[i] += a[i];
}

// ---------------------------------------------------------------- launch
extern "C" void kernel_launch(void* const* d_in, const int* in_sizes, int n_in,
                              void* d_out, int out_size, void* d_ws, size_t ws_size,
                              hipStream_t stream) {
    (void)in_sizes; (void)n_in; (void)out_size; (void)ws_size;
    const float* x      = (const float*)d_in[0];
    const float* fc     = (const float*)d_in[1];
    const float* fs     = (const float*)d_in[2];
    // d_in[3] mask: causality handled analytically
    const float* anw    = (const float*)d_in[4];
    const float* fnw    = (const float*)d_in[5];
    const float* wq     = (const float*)d_in[6];
    const float* wk     = (const float*)d_in[7];
    const float* wv     = (const float*)d_in[8];
    const float* wo     = (const float*)d_in[9];
    const float* gate_w = (const float*)d_in[10];
    const float* ew1    = (const float*)d_in[11];
    const float* ew2    = (const float*)d_in[12];
    const float* ew3    = (const float*)d_in[13];
    const float* sw1    = (const float*)d_in[14];
    const float* sw2    = (const float*)d_in[15];
    const float* sw3    = (const float*)d_in[16];
    float* out = (float*)d_out;

    char* wsp = (char*)d_ws;
    size_t off = 0;
    auto alloc = [&](size_t bytes) {
        void* p = wsp + off;
        off += (bytes + 255) & ~(size_t)255;
        return p;
    };
    float* hbuf   = (float*)alloc((size_t)T * D * 4);
    float* qbuf   = (float*)alloc((size_t)T * D * 4);
    float* kbuf   = (float*)alloc((size_t)T * D * 4);
    float* vbuf   = (float*)alloc((size_t)T * D * 4);
    float* attnb  = (float*)alloc((size_t)T * D * 4);
    float* x1     = (float*)alloc((size_t)T * D * 4);
    float* tbuf   = (float*)alloc((size_t)T * D * 4);
    float* routed = (float*)alloc((size_t)T * D * 4);
    float* logits = (float*)alloc((size_t)T * E * 4);
    float* gwbuf  = (float*)alloc((size_t)T * TK * 4);
    int*   counts = (int*)alloc(E * 4);
    int*   elist  = (int*)alloc((size_t)E * T * 4);
    float* abuf   = (float*)alloc((size_t)T * TK * I_ * 4);
    float* u1     = (float*)alloc((size_t)T * SH_I * 4);
    float* u3     = (float*)alloc((size_t)T * SH_I * 4);
    float* ub     = (float*)alloc((size_t)T * SH_I * 4);

    hipMemsetAsync(counts, 0, E * 4, stream);
    hipMemsetAsync(routed, 0, (size_t)T * D * 4, stream);

    // attention branch
    rmsnorm_kernel<<<T, 256, 0, stream>>>(x, anw, hbuf);
    // fused QKV: z selects weight/output
    mgemm_nt_kernel<<<dim3(D / 64, T / 64, 3), 256, 0, stream>>>(hbuf, wq, wk, wv,
                                                                 qbuf, kbuf, vbuf,
                                                                 nullptr, T, D, D);
    rope_kernel<<<(T * H * HD / 2) / 256, 256, 0, stream>>>(qbuf, kbuf, fc, fs);
    attn_mfma_kernel<<<dim3(S / 64, H), 256, 0, stream>>>(qbuf, kbuf, vbuf, attnb);
    mgemm_nt_kernel<<<dim3(D / 64, T / 64, 1), 256, 0, stream>>>(attnb, wo, wo, wo,
                                                                 x1, x1, x1,
                                                                 x, T, D, D);

    // FFN branch
    rmsnorm_kernel<<<T, 256, 0, stream>>>(x1, fnw, tbuf);
    gate_kernel<<<T, 256, 0, stream>>>(tbuf, gate_w, logits);
    routing_kernel<<<T, 64, 0, stream>>>(logits, gwbuf, counts, elist);
    moe_up_kernel<<<dim3(E, I_ / 64), 256, 0, stream>>>(tbuf, ew1, ew3, counts, elist, abuf);
    moe_down_kernel<<<dim3(E, D / 64), 256, 0, stream>>>(abuf, ew2, counts, elist, gwbuf, routed);

    // shared expert: sw1/sw3 fused via z
    mgemm_nt_kernel<<<dim3(SH_I / 64, T / 64, 2), 256, 0, stream>>>(tbuf, sw1, sw3, sw3,
                                                                    u1, u3, u3,
                                                                    nullptr, T, SH_I, D);
    silu_mul_kernel<<<(T * SH_I) / 256, 256, 0, stream>>>(u1, u3, ub, T * SH_I);
    mgemm_nt_kernel<<<dim3(D / 64, T / 64, 1), 256, 0, stream>>>(ub, sw2, sw2, sw2,
                                                                 out, out, out,
                                                                 x1, T, D, SH_I);
    add_inplace_kernel<<<(T * D) / 256, 256, 0, stream>>>(out, routed, T * D);
}